// Round 2
// baseline (6886.318 us; speedup 1.0000x reference)
//
#include <hip/hip_runtime.h>
#include <math.h>

// ---- problem dims ----
#define HWSZ 65160      // 181*360
#define H_ 181
#define W_ 360
#define KW_ 181         // W/2+1
#define KHW 32761       // 181*181 spectral points
#define CW_ 64          // kw chunk width (padded)
#define PC_ 11584       // 181*64 points per padded chunk
#define E_ 128
#define HID_ 256
#define L_ 4

__device__ __forceinline__ float gelu_f(float x){
    return 0.5f*x*(1.0f+erff(x*0.70710678118654752f));
}

// ---- twiddle tables (ortho norm folded into W-stage matrices) ----
__global__ void k_twiddle(float* __restrict__ cwf, float* __restrict__ swf,
                          float* __restrict__ ch,  float* __restrict__ sh,
                          float* __restrict__ cwi, float* __restrict__ swi){
    int i = blockIdx.x*256 + threadIdx.x;
    const float inv = 1.0f/sqrtf((float)(H_*W_));
    const float TWO_PI = 6.28318530717958647692f;
    if(i < W_*KW_){               // forward W DFT: [w][kw]
        int w = i/KW_, kw = i - w*KW_;
        int m = (w*kw) % W_;
        float th = TWO_PI*(float)m/(float)W_;
        cwf[i] =  cosf(th)*inv;
        swf[i] = -sinf(th)*inv;   // Xim = -sum x*sin
    }
    if(i < KHW){                  // H DFT twiddles: [kh][h]
        int kh = i/H_, h = i - kh*H_;
        int m = (kh*h) % H_;
        float th = TWO_PI*(float)m/(float)H_;
        ch[i] = cosf(th); sh[i] = sinf(th);
    }
    if(i < KW_*W_){               // inverse W DFT: [kw][w], eps & norm folded
        int kw = i/W_, w = i - kw*W_;
        int m = (w*kw) % W_;
        float th = TWO_PI*(float)m/(float)W_;
        float eps = (kw==0 || kw==KW_-1) ? 1.0f : 2.0f;
        cwi[i] = eps*cosf(th)*inv;
        swi[i] = eps*sinf(th)*inv;
    }
}

// ---- encoder first conv (CIN=2) + gelu, pointwise ----
__global__ void k_enc0(const float* __restrict__ x, const float* __restrict__ w,
                       const float* __restrict__ b, float* __restrict__ out){
    int i = blockIdx.x*256 + threadIdx.x;
    if(i >= E_*HWSZ) return;
    int e = i/HWSZ, p = i - e*HWSZ;
    float v = fmaf(w[e*2+0], x[p], fmaf(w[e*2+1], x[HWSZ+p], b[e]));
    out[i] = gelu_f(v);
}

// ---- generic conv1x1 GEMM: out[M][P] = W[M][K]*X (+bias)(gelu)(+add) ----
__global__ __launch_bounds__(256) void k_conv(
    const float* __restrict__ Wt, const float* __restrict__ X,
    const float* __restrict__ X2, const float* __restrict__ bias,
    const float* __restrict__ add, float* __restrict__ out,
    int M, int K, int K1, int dogelu)
{
    const int P = HWSZ;
    __shared__ float As[16][68];
    __shared__ float Bs[16][68];
    int tid = threadIdx.x;
    int tx = tid & 15, ty = tid >> 4;
    int m0 = blockIdx.y*64, p0 = blockIdx.x*64;
    float acc[4][4] = {};
    for(int k0 = 0; k0 < K; k0 += 16){
        #pragma unroll
        for(int r=0;r<4;r++){
            int idx = tid + 256*r;
            int kk = idx & 15, mm = idx >> 4;
            int k = k0+kk;
            As[kk][mm] = (k<K) ? Wt[(m0+mm)*K + k] : 0.0f;
        }
        #pragma unroll
        for(int r=0;r<4;r++){
            int idx = tid + 256*r;
            int kk = idx >> 6, pp = idx & 63;
            int k = k0+kk, p = p0+pp;
            float v = 0.0f;
            if(k<K && p<P) v = (k < K1) ? X[(size_t)k*P + p] : X2[(size_t)(k-K1)*P + p];
            Bs[kk][pp] = v;
        }
        __syncthreads();
        #pragma unroll
        for(int kk=0;kk<16;kk++){
            float a[4], b[4];
            #pragma unroll
            for(int i=0;i<4;i++) a[i] = As[kk][ty*4+i];
            #pragma unroll
            for(int j=0;j<4;j++) b[j] = Bs[kk][tx*4+j];
            #pragma unroll
            for(int i=0;i<4;i++)
                #pragma unroll
                for(int j=0;j<4;j++)
                    acc[i][j] = fmaf(a[i], b[j], acc[i][j]);
        }
        __syncthreads();
    }
    #pragma unroll
    for(int i=0;i<4;i++){
        int m = m0 + ty*4 + i;
        float bv = bias ? bias[m] : 0.0f;
        #pragma unroll
        for(int j=0;j<4;j++){
            int p = p0 + tx*4 + j;
            if(p < P){
                float v = acc[i][j] + bv;
                if(dogelu) v = gelu_f(v);
                if(add) v += add[(size_t)m*P + p];
                out[(size_t)m*P + p] = v;
            }
        }
    }
}

// ---- forward W DFT: [R=E*H rows][360] x [360][181] -> re,im ----
__global__ __launch_bounds__(256) void k_rdft(
    const float* __restrict__ X, const float* __restrict__ Cw,
    const float* __restrict__ Sw, float* __restrict__ ore, float* __restrict__ oim)
{
    __shared__ float As[16][68];
    __shared__ float Cs[16][68], Ss[16][68];
    int tid=threadIdx.x, tx=tid&15, ty=tid>>4;
    int r0 = blockIdx.y*64, n0 = blockIdx.x*64;
    float accre[4][4]={}, accim[4][4]={};
    for(int k0=0;k0<W_;k0+=16){
        #pragma unroll
        for(int r=0;r<4;r++){
            int idx=tid+256*r; int kk=idx&15, rr=idx>>4;
            int k=k0+kk;
            As[kk][rr] = (k<W_) ? X[(size_t)(r0+rr)*W_ + k] : 0.0f;
        }
        #pragma unroll
        for(int r=0;r<4;r++){
            int idx=tid+256*r; int kk=idx>>6, nn=idx&63;
            int k=k0+kk, n=n0+nn;
            float c=0.0f, s=0.0f;
            if(k<W_ && n<KW_){ c=Cw[k*KW_+n]; s=Sw[k*KW_+n]; }
            Cs[kk][nn]=c; Ss[kk][nn]=s;
        }
        __syncthreads();
        #pragma unroll
        for(int kk=0;kk<16;kk++){
            float a[4], c[4], s[4];
            #pragma unroll
            for(int i=0;i<4;i++) a[i]=As[kk][ty*4+i];
            #pragma unroll
            for(int j=0;j<4;j++){ c[j]=Cs[kk][tx*4+j]; s[j]=Ss[kk][tx*4+j]; }
            #pragma unroll
            for(int i=0;i<4;i++)
                #pragma unroll
                for(int j=0;j<4;j++){
                    accre[i][j]=fmaf(a[i],c[j],accre[i][j]);
                    accim[i][j]=fmaf(a[i],s[j],accim[i][j]);
                }
        }
        __syncthreads();
    }
    #pragma unroll
    for(int i=0;i<4;i++){
        int rr = r0 + ty*4 + i;
        #pragma unroll
        for(int j=0;j<4;j++){
            int n = n0 + tx*4 + j;
            if(n < KW_){
                ore[(size_t)rr*KW_+n] = accre[i][j];
                oim[(size_t)rr*KW_+n] = accim[i][j];
            }
        }
    }
}

// ---- H-axis complex DFT on a kw chunk (batched over channel) ----
// out[m][j] = sum_k (Tc[m][k] - i*sg*Ts[m][k]) * z[k][j]
__global__ __launch_bounds__(256) void k_cdfth_chunk(
    const float* __restrict__ Tc, const float* __restrict__ Ts,
    const float* __restrict__ zre, const float* __restrict__ zim,
    float* __restrict__ ore, float* __restrict__ oim, float sg,
    int in_stride, int in_cstride, int out_stride, int out_cstride,
    int nread, int nwrite)
{
    int c = blockIdx.z;
    const float* zr = zre + (size_t)c*in_cstride;
    const float* zi = zim + (size_t)c*in_cstride;
    float* outr = ore + (size_t)c*out_cstride;
    float* outi = oim + (size_t)c*out_cstride;
    __shared__ float Ac[16][68], Asn[16][68], Br[16][68], Bi[16][68];
    int tid=threadIdx.x, tx=tid&15, ty=tid>>4;
    int m0=blockIdx.y*64;
    float accre[4][4]={}, accim[4][4]={};
    for(int k0=0;k0<H_;k0+=16){
        #pragma unroll
        for(int r=0;r<4;r++){
            int idx=tid+256*r; int kk=idx&15, mm=idx>>4;
            int k=k0+kk, m=m0+mm;
            float cv=0.0f, sv=0.0f;
            if(k<H_ && m<H_){ cv=Tc[m*H_+k]; sv=Ts[m*H_+k]; }
            Ac[kk][mm]=cv; Asn[kk][mm]=sv*sg;
        }
        #pragma unroll
        for(int r=0;r<4;r++){
            int idx=tid+256*r; int kk=idx>>6, jj=idx&63;
            int k=k0+kk;
            float vr=0.0f, vi=0.0f;
            if(k<H_ && jj<nread){ vr=zr[(size_t)k*in_stride+jj]; vi=zi[(size_t)k*in_stride+jj]; }
            Br[kk][jj]=vr; Bi[kk][jj]=vi;
        }
        __syncthreads();
        #pragma unroll
        for(int kk=0;kk<16;kk++){
            float ac[4], as[4], br[4], bi[4];
            #pragma unroll
            for(int i=0;i<4;i++){ ac[i]=Ac[kk][ty*4+i]; as[i]=Asn[kk][ty*4+i]; }
            #pragma unroll
            for(int j=0;j<4;j++){ br[j]=Br[kk][tx*4+j]; bi[j]=Bi[kk][tx*4+j]; }
            #pragma unroll
            for(int i=0;i<4;i++)
                #pragma unroll
                for(int j=0;j<4;j++){
                    accre[i][j]=fmaf(ac[i],br[j],accre[i][j]);
                    accre[i][j]=fmaf(as[i],bi[j],accre[i][j]);
                    accim[i][j]=fmaf(ac[i],bi[j],accim[i][j]);
                    accim[i][j]=fmaf(-as[i],br[j],accim[i][j]);
                }
        }
        __syncthreads();
    }
    #pragma unroll
    for(int i=0;i<4;i++){
        int m = m0 + ty*4 + i;
        #pragma unroll
        for(int j=0;j<4;j++){
            int jj = tx*4 + j;
            if(m<H_ && jj<nwrite){
                outr[(size_t)m*out_stride+jj]=accre[i][j];
                outi[(size_t)m*out_stride+jj]=accim[i][j];
            }
        }
    }
}

// ---- complex channel mixing on a chunk: out[M][P] = sum_k W[k][m]*z[k][p] ----
__global__ __launch_bounds__(256) void k_cmix(
    const float* __restrict__ Wre, const float* __restrict__ Wim,
    const float* __restrict__ zre, const float* __restrict__ zim,
    float* __restrict__ ore, float* __restrict__ oim,
    int M, int K, int P, int dorelu)
{
    __shared__ float Ar[16][68], Ai[16][68], Br[16][68], Bi[16][68];
    int tid=threadIdx.x, tx=tid&15, ty=tid>>4;
    int m0=blockIdx.y*64, p0=blockIdx.x*64;
    float accre[4][4]={}, accim[4][4]={};
    for(int k0=0;k0<K;k0+=16){
        #pragma unroll
        for(int r=0;r<4;r++){
            int idx=tid+256*r; int kk=idx>>6, mm=idx&63;
            int k=k0+kk;
            float vr=0.0f, vi=0.0f;
            if(k<K){ vr=Wre[k*M + m0+mm]; vi=Wim[k*M + m0+mm]; }
            Ar[kk][mm]=vr; Ai[kk][mm]=vi;
        }
        #pragma unroll
        for(int r=0;r<4;r++){
            int idx=tid+256*r; int kk=idx>>6, pp=idx&63;
            int k=k0+kk, p=p0+pp;
            float vr=0.0f, vi=0.0f;
            if(k<K && p<P){ vr=zre[(size_t)k*P+p]; vi=zim[(size_t)k*P+p]; }
            Br[kk][pp]=vr; Bi[kk][pp]=vi;
        }
        __syncthreads();
        #pragma unroll
        for(int kk=0;kk<16;kk++){
            float ar[4], ai[4], br[4], bi[4];
            #pragma unroll
            for(int i=0;i<4;i++){ ar[i]=Ar[kk][ty*4+i]; ai[i]=Ai[kk][ty*4+i]; }
            #pragma unroll
            for(int j=0;j<4;j++){ br[j]=Br[kk][tx*4+j]; bi[j]=Bi[kk][tx*4+j]; }
            #pragma unroll
            for(int i=0;i<4;i++)
                #pragma unroll
                for(int j=0;j<4;j++){
                    accre[i][j]=fmaf(ar[i],br[j],accre[i][j]);
                    accre[i][j]=fmaf(-ai[i],bi[j],accre[i][j]);
                    accim[i][j]=fmaf(ar[i],bi[j],accim[i][j]);
                    accim[i][j]=fmaf(ai[i],br[j],accim[i][j]);
                }
        }
        __syncthreads();
    }
    #pragma unroll
    for(int i=0;i<4;i++){
        int m = m0 + ty*4 + i;
        #pragma unroll
        for(int j=0;j<4;j++){
            int p = p0 + tx*4 + j;
            if(p<P){
                float vr = accre[i][j];
                if(dorelu) vr = fmaxf(vr, 0.0f);   // CReLU: relu on real only
                ore[(size_t)m*P+p]=vr;
                oim[(size_t)m*P+p]=accim[i][j];
            }
        }
    }
}

// ---- inverse W DFT: y[R][360] = sum_kw Yre*Cwi - Yim*Swi ----
__global__ __launch_bounds__(256) void k_irdft(
    const float* __restrict__ yre, const float* __restrict__ yim,
    const float* __restrict__ Cw, const float* __restrict__ Sw,
    float* __restrict__ out)
{
    __shared__ float Ar[16][68], Ai[16][68], Cs[16][68], Ss[16][68];
    int tid=threadIdx.x, tx=tid&15, ty=tid>>4;
    int r0 = blockIdx.y*64, n0 = blockIdx.x*64;
    float acc[4][4]={};
    for(int k0=0;k0<KW_;k0+=16){
        #pragma unroll
        for(int r=0;r<4;r++){
            int idx=tid+256*r; int kk=idx&15, rr=idx>>4;
            int k=k0+kk;
            float vr=0.0f, vi=0.0f;
            if(k<KW_){ vr=yre[(size_t)(r0+rr)*KW_+k]; vi=yim[(size_t)(r0+rr)*KW_+k]; }
            Ar[kk][rr]=vr; Ai[kk][rr]=vi;
        }
        #pragma unroll
        for(int r=0;r<4;r++){
            int idx=tid+256*r; int kk=idx>>6, nn=idx&63;
            int k=k0+kk, n=n0+nn;
            float c=0.0f, s=0.0f;
            if(k<KW_ && n<W_){ c=Cw[k*W_+n]; s=Sw[k*W_+n]; }
            Cs[kk][nn]=c; Ss[kk][nn]=s;
        }
        __syncthreads();
        #pragma unroll
        for(int kk=0;kk<16;kk++){
            float ar[4], ai[4], c[4], s[4];
            #pragma unroll
            for(int i=0;i<4;i++){ ar[i]=Ar[kk][ty*4+i]; ai[i]=Ai[kk][ty*4+i]; }
            #pragma unroll
            for(int j=0;j<4;j++){ c[j]=Cs[kk][tx*4+j]; s[j]=Ss[kk][tx*4+j]; }
            #pragma unroll
            for(int i=0;i<4;i++)
                #pragma unroll
                for(int j=0;j<4;j++){
                    acc[i][j]=fmaf(ar[i],c[j],acc[i][j]);
                    acc[i][j]=fmaf(-ai[i],s[j],acc[i][j]);
                }
        }
        __syncthreads();
    }
    #pragma unroll
    for(int i=0;i<4;i++){
        int rr = r0 + ty*4 + i;
        #pragma unroll
        for(int j=0;j<4;j++){
            int n = n0 + tx*4 + j;
            if(n < W_) out[(size_t)rr*W_+n] = acc[i][j];
        }
    }
}

// ---- instance norm (per channel over H*W) ----
__global__ __launch_bounds__(256) void k_inorm(
    const float* __restrict__ in, float* __restrict__ out,
    const float* __restrict__ w, const float* __restrict__ b)
{
    int c = blockIdx.x;
    const float* xp = in + (size_t)c*HWSZ;
    float* op = out + (size_t)c*HWSZ;
    float s=0.0f, s2=0.0f;
    for(int i=threadIdx.x; i<HWSZ; i+=256){ float v=xp[i]; s+=v; s2=fmaf(v,v,s2); }
    __shared__ float rs[256], rs2[256];
    __shared__ float stats[2];
    rs[threadIdx.x]=s; rs2[threadIdx.x]=s2;
    __syncthreads();
    for(int st=128; st>0; st>>=1){
        if(threadIdx.x < st){ rs[threadIdx.x]+=rs[threadIdx.x+st]; rs2[threadIdx.x]+=rs2[threadIdx.x+st]; }
        __syncthreads();
    }
    if(threadIdx.x==0){
        float mu = rs[0]/(float)HWSZ;
        float var = rs2[0]/(float)HWSZ - mu*mu;
        if(var < 0.0f) var = 0.0f;
        stats[0]=mu; stats[1]=1.0f/sqrtf(var + 1e-6f);
    }
    __syncthreads();
    float mu = stats[0], rstd = stats[1];
    float gw = w[c], gb = b[c];
    for(int i=threadIdx.x; i<HWSZ; i+=256){
        op[i] = fmaf((xp[i]-mu)*rstd, gw, gb);
    }
}

// ---- final decoder conv: out[2][P] = dec_w1[2][128] * hid ----
__global__ void k_dec1(const float* __restrict__ hid, const float* __restrict__ w,
                       float* __restrict__ out){
    int p = blockIdx.x*256 + threadIdx.x;
    if(p >= HWSZ) return;
    float a0=0.0f, a1=0.0f;
    for(int k=0;k<E_;k++){
        float h = hid[(size_t)k*HWSZ + p];
        a0 = fmaf(w[k], h, a0);
        a1 = fmaf(w[E_+k], h, a1);
    }
    out[p]=a0; out[HWSZ+p]=a1;
}

extern "C" void kernel_launch(void* const* d_in, const int* in_sizes, int n_in,
                              void* d_out, int out_size, void* d_ws, size_t ws_size,
                              hipStream_t stream) {
    const float* x       = (const float*)d_in[0];
    const float* enc_w0  = (const float*)d_in[1];
    const float* enc_b0  = (const float*)d_in[2];
    const float* enc_w1  = (const float*)d_in[3];
    const float* pos     = (const float*)d_in[4];
    const float* n0w     = (const float*)d_in[5];
    const float* n0b     = (const float*)d_in[6];
    const float* w0      = (const float*)d_in[7];
    const float* w1      = (const float*)d_in[8];
    const float* wout    = (const float*)d_in[9];
    const float* isw     = (const float*)d_in[10];
    const float* isb     = (const float*)d_in[11];
    const float* n1w     = (const float*)d_in[12];
    const float* n1b     = (const float*)d_in[13];
    const float* fc1w    = (const float*)d_in[14];
    const float* fc1b    = (const float*)d_in[15];
    const float* fc2w    = (const float*)d_in[16];
    const float* fc2b    = (const float*)d_in[17];
    const float* dec_w0  = (const float*)d_in[18];
    const float* dec_b0  = (const float*)d_in[19];
    const float* dec_w1  = (const float*)d_in[20];
    float* out = (float*)d_out;

    float* ws = (float*)d_ws;
    size_t off = 0;
    auto alloc = [&](size_t n){ float* p = ws + off; off += n; return p; };
    float* cwf = alloc(W_*KW_);
    float* swf = alloc(W_*KW_);
    float* ch  = alloc(KHW);
    float* sh  = alloc(KHW);
    float* cwi = alloc(KW_*W_);
    float* swi = alloc(KW_*W_);
    float* CUR = alloc((size_t)E_*HWSZ);      // 33.4 MB
    float* XN  = alloc((size_t)E_*HWSZ);      // 33.4 MB
    float* SAre = alloc((size_t)E_*KHW);      // 16.8 MB
    float* SAim = alloc((size_t)E_*KHW);      // 16.8 MB
    float* Zcre = alloc((size_t)E_*PC_);      //  5.9 MB
    float* Zcim = alloc((size_t)E_*PC_);      //  5.9 MB
    float* H1re = alloc((size_t)HID_*PC_);    // 11.9 MB
    float* H1im = alloc((size_t)HID_*PC_);    // 11.9 MB
    float* H2re = alloc((size_t)HID_*PC_);    // 11.9 MB
    float* H2im = alloc((size_t)HID_*PC_);    // 11.9 MB
    // total: 40,221,458 floats = 160.9 MB
    // MLP scratch (HID_*HWSZ = 16,680,960 floats) aliases SA..H1 (17,283,328 floats),
    // all of which are dead by the time fc1 runs.
    float* MLPT = SAre;

    dim3 blk(256);
    k_twiddle<<<dim3((HWSZ+255)/256), blk, 0, stream>>>(cwf,swf,ch,sh,cwi,swi);
    // encoder (XN as temp)
    k_enc0<<<dim3(((size_t)E_*HWSZ+255)/256), blk, 0, stream>>>(x, enc_w0, enc_b0, XN);
    k_conv<<<dim3((HWSZ+63)/64, E_/64), blk, 0, stream>>>(enc_w1, XN, nullptr, nullptr, pos, CUR, E_, E_, E_, 0);

    const int gP = (HWSZ+63)/64;       // 1019
    const int gC = (PC_+63)/64;        // 181
    const int gK = (KW_+63)/64;        // 3
    const int gR = (E_*H_)/64;         // 362
    const int gW = (W_+63)/64;         // 6
    const int kw0s[3] = {0, 64, 128};
    const int cws[3]  = {64, 64, 53};

    for(int l=0; l<L_; l++){
        const float* n0w_l = n0w + l*E_;   const float* n0b_l = n0b + l*E_;
        const float* w0re = w0 + (size_t)l*2*E_*HID_;   const float* w0im = w0re + E_*HID_;
        const float* w1re = w1 + (size_t)l*2*HID_*HID_; const float* w1im = w1re + HID_*HID_;
        const float* wore = wout + (size_t)l*2*HID_*E_; const float* woim = wore + HID_*E_;
        const float* isw_l = isw + (size_t)l*E_*E_;     const float* isb_l = isb + l*E_;
        const float* n1w_l = n1w + l*E_;   const float* n1b_l = n1b + l*E_;
        const float* fc1w_l = fc1w + (size_t)l*HID_*E_; const float* fc1b_l = fc1b + l*HID_;
        const float* fc2w_l = fc2w + (size_t)l*E_*HID_; const float* fc2b_l = fc2b + l*E_;

        k_inorm<<<dim3(E_), blk, 0, stream>>>(CUR, XN, n0w_l, n0b_l);
        k_rdft <<<dim3(gK, gR), blk, 0, stream>>>(XN, cwf, swf, SAre, SAim);
        // spectral channel-MLP, chunked over kw (CUR is dead here)
        for(int cidx=0; cidx<3; cidx++){
            int kw0 = kw0s[cidx], cw = cws[cidx];
            k_cdfth_chunk<<<dim3(1, gK, E_), blk, 0, stream>>>(
                ch, sh, SAre+kw0, SAim+kw0, Zcre, Zcim, 1.0f,
                KW_, KHW, CW_, PC_, cw, CW_);
            k_cmix<<<dim3(gC, HID_/64), blk, 0, stream>>>(w0re, w0im, Zcre, Zcim, H1re, H1im, HID_, E_,  PC_, 1);
            k_cmix<<<dim3(gC, HID_/64), blk, 0, stream>>>(w1re, w1im, H1re, H1im, H2re, H2im, HID_, HID_, PC_, 1);
            k_cmix<<<dim3(gC, E_/64),   blk, 0, stream>>>(wore, woim, H2re, H2im, Zcre, Zcim, E_,  HID_, PC_, 0);
            k_cdfth_chunk<<<dim3(1, gK, E_), blk, 0, stream>>>(
                ch, sh, Zcre, Zcim, SAre+kw0, SAim+kw0, -1.0f,
                CW_, PC_, KW_, KHW, CW_, cw);
        }
        k_irdft<<<dim3(gW, gR), blk, 0, stream>>>(SAre, SAim, cwi, swi, CUR);
        // inner skip: CUR = isw*XN + isb + CUR(fft branch)
        k_conv<<<dim3(gP, E_/64), blk, 0, stream>>>(isw_l, XN, nullptr, isb_l, CUR, CUR, E_, E_, E_, 0);
        k_inorm<<<dim3(E_), blk, 0, stream>>>(CUR, CUR, n1w_l, n1b_l);
        k_conv<<<dim3(gP, HID_/64), blk, 0, stream>>>(fc1w_l, CUR, nullptr, fc1b_l, nullptr, MLPT, HID_, E_, E_, 1);
        // outer skip: CUR = fc2*MLPT + fc2b + XN
        k_conv<<<dim3(gP, E_/64), blk, 0, stream>>>(fc2w_l, MLPT, nullptr, fc2b_l, XN, CUR, E_, HID_, HID_, 0);
    }
    // decoder: XN = gelu(dec_w0 * [CUR ; x] + dec_b0), K=130 split at 128
    k_conv<<<dim3(gP, E_/64), blk, 0, stream>>>(dec_w0, CUR, x, dec_b0, nullptr, XN, E_, E_+2, E_, 1);
    k_dec1<<<dim3((HWSZ+255)/256), blk, 0, stream>>>(XN, dec_w1, out);
}

// Round 3
// 2519.176 us; speedup vs baseline: 2.7336x; 2.7336x over previous
//
#include <hip/hip_runtime.h>
#include <math.h>

#define HWSZ 65160
#define H_ 181
#define W_ 360
#define PC_ 11584       // 181*64 chunk points
#define E_ 128
#define HID_ 256
#define L_ 4

typedef unsigned short u16;
typedef __attribute__((ext_vector_type(8))) short bf16x8;
typedef __attribute__((ext_vector_type(4))) float f32x4;
typedef __attribute__((ext_vector_type(4))) unsigned short us4;

__device__ __forceinline__ u16 f2bf(float f){
    unsigned u = __builtin_bit_cast(unsigned, f);
    return (u16)((u + 0x7FFFu + ((u>>16)&1u)) >> 16);
}
__device__ __forceinline__ float bf2f(u16 h){
    unsigned u = ((unsigned)h)<<16;
    return __builtin_bit_cast(float, u);
}
__device__ __forceinline__ float gelu_f(float x){
    return 0.5f*x*(1.0f+erff(x*0.70710678118654752f));
}

// ================== prepack kernels ==================
// TWF [384 rows=k(w)][384 cols=n]: n<192: kw=n -> cos*inv ; n>=192: kw=n-192 -> -sin*inv
__global__ void k_prep_twf(u16* __restrict__ dst){
    int i = blockIdx.x*256 + threadIdx.x;
    if(i >= 384*384) return;
    int k = i/384, n = i - k*384;
    float v = 0.0f;
    const float inv = 1.0f/sqrtf((float)(H_*W_));
    const float TP = 6.28318530717958647692f;
    if(k < W_){
        int kw = (n < 192) ? n : n-192;
        if(kw < 181){
            float th = TP*(float)((k*kw)%W_)/(float)W_;
            v = (n < 192) ? cosf(th)*inv : -sinf(th)*inv;
        }
    }
    dst[i] = f2bf(v);
}
// TH: two matrices [384][384], interleaved rows m=2kh+p, cols k=2h+q
__global__ void k_prep_th(u16* __restrict__ dst){
    int i = blockIdx.x*256 + threadIdx.x;
    if(i >= 2*384*384) return;
    int t = i/(384*384), r = i - t*384*384;
    int m = r/384, k = r - m*384;
    float v = 0.0f;
    const float TP = 6.28318530717958647692f;
    if(m < 362 && k < 362){
        int kh = m>>1, pm = m&1, h = k>>1, pk = k&1;
        float th = TP*(float)((kh*h)%H_)/(float)H_;
        float c = cosf(th), s = sinf(th);
        if(t == 0){ // forward: re-row [C|+S], im-row [-S|C]
            v = (pm==0) ? (pk==0? c : s) : (pk==0? -s : c);
        } else {    // inverse: re-row [C|-S], im-row [S|C]
            v = (pm==0) ? (pk==0? c : -s) : (pk==0? s : c);
        }
    }
    dst[i] = f2bf(v);
}
// TWI [384 rows=k][360 cols=w]: k<181: eps*cos*inv ; 192<=k<373: -eps*sin*inv ; else 0
__global__ void k_prep_twi(u16* __restrict__ dst){
    int i = blockIdx.x*256 + threadIdx.x;
    if(i >= 384*360) return;
    int k = i/360, w = i - k*360;
    float v = 0.0f;
    const float inv = 1.0f/sqrtf((float)(H_*W_));
    const float TP = 6.28318530717958647692f;
    int kw = -1; int isim = 0;
    if(k < 181){ kw = k; }
    else if(k >= 192 && k < 373){ kw = k-192; isim = 1; }
    if(kw >= 0){
        float eps = (kw==0 || kw==180) ? 1.0f : 2.0f;
        float th = TP*(float)((w*kw)%W_)/(float)W_;
        v = isim ? -eps*sinf(th)*inv : eps*cosf(th)*inv;
    }
    dst[i] = f2bf(v);
}
// complex weight stack: src [2][K][M] f32 -> dst [2M][2K] bf16 interleaved rows/cols
__global__ void k_prep_cw(const float* __restrict__ src, u16* __restrict__ dst, int K, int M){
    int i = blockIdx.x*256 + threadIdx.x;
    if(i >= 4*K*M) return;
    int K2 = 2*K;
    int mr = i / K2, kc = i - mr*K2;
    int m = mr>>1, p = mr&1, ci = kc>>1, q = kc&1;
    float re = src[ci*M + m];
    float im = src[(size_t)K*M + ci*M + m];
    float v = p ? (q ? im : im*0.0f + im) : (q ? -im : re);
    // p==0 (re-out): q0 -> re, q1 -> -im ; p==1 (im-out): q0 -> im, q1 -> re
    v = (p==0) ? (q==0 ? re : -im) : (q==0 ? im : re);
    dst[i] = f2bf(v);
}
// real weight: src [M][Ks] f32 -> dst [M][Kp] bf16 zero-padded
__global__ void k_prep_w(const float* __restrict__ src, u16* __restrict__ dst, int M, int Ks, int Kp){
    int i = blockIdx.x*256 + threadIdx.x;
    if(i >= M*Kp) return;
    int m = i/Kp, k = i - m*Kp;
    dst[i] = f2bf(k < Ks ? src[(size_t)m*Ks + k] : 0.0f);
}

// ================== pointwise kernels ==================
__global__ void k_enc0(const float* __restrict__ x, const float* __restrict__ w,
                       const float* __restrict__ b, u16* __restrict__ out){
    int i = blockIdx.x*256 + threadIdx.x;
    if(i >= E_*HWSZ) return;
    int e = i/HWSZ, p = i - e*HWSZ;
    float v = fmaf(w[e*2+0], x[p], fmaf(w[e*2+1], x[HWSZ+p], b[e]));
    out[i] = f2bf(gelu_f(v));
}

__global__ __launch_bounds__(256) void k_inorm(
    const u16* __restrict__ in, u16* __restrict__ out,
    const float* __restrict__ w, const float* __restrict__ b)
{
    int c = blockIdx.x;
    const u16* xp = in + (size_t)c*HWSZ;
    u16* op = out + (size_t)c*HWSZ;
    float s=0.0f, s2=0.0f;
    for(int i=threadIdx.x; i<HWSZ/4; i+=256){
        us4 v = *(const us4*)(xp + i*4);
        #pragma unroll
        for(int j=0;j<4;j++){ float f = bf2f(v[j]); s += f; s2 = fmaf(f,f,s2); }
    }
    __shared__ float rs[256], rs2[256];
    __shared__ float stats[2];
    rs[threadIdx.x]=s; rs2[threadIdx.x]=s2;
    __syncthreads();
    for(int st=128; st>0; st>>=1){
        if(threadIdx.x < st){ rs[threadIdx.x]+=rs[threadIdx.x+st]; rs2[threadIdx.x]+=rs2[threadIdx.x+st]; }
        __syncthreads();
    }
    if(threadIdx.x==0){
        float mu = rs[0]/(float)HWSZ;
        float var = rs2[0]/(float)HWSZ - mu*mu;
        if(var < 0.0f) var = 0.0f;
        stats[0]=mu; stats[1]=1.0f/sqrtf(var + 1e-6f);
    }
    __syncthreads();
    float mu = stats[0], rstd = stats[1];
    float gw = w[c], gb = b[c];
    for(int i=threadIdx.x; i<HWSZ/4; i+=256){
        us4 v = *(const us4*)(xp + i*4);
        us4 o;
        #pragma unroll
        for(int j=0;j<4;j++) o[j] = f2bf(fmaf((bf2f(v[j])-mu)*rstd, gw, gb));
        *(us4*)(op + i*4) = o;
    }
}

__global__ void k_dec1(const u16* __restrict__ hid, const float* __restrict__ w,
                       float* __restrict__ out){
    int p = blockIdx.x*256 + threadIdx.x;
    if(p >= HWSZ) return;
    float a0=0.0f, a1=0.0f;
    for(int k=0;k<E_;k++){
        float h = bf2f(hid[(size_t)k*HWSZ + p]);
        a0 = fmaf(w[k], h, a0);
        a1 = fmaf(w[E_+k], h, a1);
    }
    out[p]=a0; out[HWSZ+p]=a1;
}

// ================== generic MFMA GEMM ==================
// C[m][n] = sum_k A[m][k] * B[k][n]
// A: bf16 row-major [m][lda], k-contig, fully readable (pads zero or harmless)
// B addr = sel_plane + (ke&1)*psB + (ke>>1)*ldb2 + (n>>bshift)*bstr + (n&bmask)
//          + (bnoffz? z*64 : 0) + z*bzstr     (plane: ke=k0+e<K1 ? B1 : B2 with ke-=K1)
// C addr = (m&1)*psC + (m>>1)*ldc2 + (n>>cshift)*cstr + (n&cmask) + (cnoffz? z*64:0) + z*czstr
// flags: 1=gelu, 2=relu, 4=relu-even-rows-only
__global__ __launch_bounds__(256) void k_gemm(
    const u16* __restrict__ A, int lda,
    const u16* __restrict__ B1, const u16* __restrict__ B2, int K1,
    long psB, long ldb2, int bshift, long bstr, int bnoffz, long bzstr,
    u16* __restrict__ C, long psC, long ldc2, int cshift, long cstr, int cnoffz, long czstr, int cjmax,
    const float* __restrict__ bias, const u16* __restrict__ addb, const float* __restrict__ addf,
    int M, int N, int Kpad, int flags)
{
    int z = blockIdx.z;
    int tid = threadIdx.x;
    int l = tid & 63, wv = tid >> 6;
    int wm = wv >> 1, wn = wv & 1;
    int lm = l & 15, kg = l >> 4;
    long m0 = (long)blockIdx.y * 128 + wm*64;
    long n0 = (long)blockIdx.x * 128 + wn*64;

    unsigned aoff[4];
    #pragma unroll
    for(int i2=0;i2<4;i2++){
        long mi = m0 + i2*16 + lm;
        aoff[i2] = (unsigned)(mi * lda + kg*8);
    }
    unsigned nboff[4];
    int bmask = (1<<bshift)-1;
    #pragma unroll
    for(int j2=0;j2<4;j2++){
        long n = n0 + j2*16 + lm;
        long v = (n>>bshift)*bstr + (n & bmask) + (bnoffz ? (long)z*64 : 0) + (long)z*bzstr + (long)kg*4*ldb2;
        nboff[j2] = (unsigned)v;
    }
    f32x4 acc[4][4];
    #pragma unroll
    for(int i2=0;i2<4;i2++)
        #pragma unroll
        for(int j2=0;j2<4;j2++)
            acc[i2][j2] = (f32x4){0.0f,0.0f,0.0f,0.0f};

    for(int k0=0; k0<Kpad; k0+=32){
        bf16x8 af[4];
        #pragma unroll
        for(int i2=0;i2<4;i2++)
            af[i2] = *(const bf16x8*)(A + aoff[i2] + k0);

        const u16* sb[8];
        #pragma unroll
        for(int e=0;e<8;e++){
            int ke = k0 + e;
            const u16* bb = B1;
            if(ke >= K1){ bb = B2; ke -= K1; }
            sb[e] = bb + (long)(ke&1)*psB + (long)(ke>>1)*ldb2;
        }
        bf16x8 bf[4];
        #pragma unroll
        for(int j2=0;j2<4;j2++){
            #pragma unroll
            for(int e=0;e<8;e++) bf[j2][e] = (short)sb[e][nboff[j2]];
        }
        #pragma unroll
        for(int i2=0;i2<4;i2++)
            #pragma unroll
            for(int j2=0;j2<4;j2++)
                acc[i2][j2] = __builtin_amdgcn_mfma_f32_16x16x32_bf16(af[i2], bf[j2], acc[i2][j2], 0,0,0);
    }

    int cm = (1<<cshift)-1;
    int jmaxe = cjmax - (cnoffz ? z*64 : 0);
    #pragma unroll
    for(int i2=0;i2<4;i2++){
        #pragma unroll
        for(int r=0;r<4;r++){
            long m = m0 + i2*16 + kg*4 + r;
            if(m >= M) continue;
            float bv = bias ? bias[m] : 0.0f;
            long mterm = (m&1)*psC + (m>>1)*ldc2 + (cnoffz ? (long)z*64 : 0) + (long)z*czstr;
            int dorelu = (flags & 2) && (!(flags & 4) || ((m&1)==0));
            #pragma unroll
            for(int j2=0;j2<4;j2++){
                long n = n0 + j2*16 + lm;
                if(n >= N) continue;
                int j = (int)(n & cm);
                if(j >= jmaxe) continue;
                long caddr = (n>>cshift)*cstr + j + mterm;
                float v = acc[i2][j2][r] + bv;
                if(flags & 1) v = gelu_f(v);
                if(dorelu) v = fmaxf(v, 0.0f);
                if(addb) v += bf2f(addb[caddr]);
                if(addf) v += addf[caddr];
                C[caddr] = f2bf(v);
            }
        }
    }
}

// ================== launch ==================
extern "C" void kernel_launch(void* const* d_in, const int* in_sizes, int n_in,
                              void* d_out, int out_size, void* d_ws, size_t ws_size,
                              hipStream_t stream) {
    const float* x       = (const float*)d_in[0];
    const float* enc_w0  = (const float*)d_in[1];
    const float* enc_b0  = (const float*)d_in[2];
    const float* enc_w1  = (const float*)d_in[3];
    const float* pos     = (const float*)d_in[4];
    const float* n0w     = (const float*)d_in[5];
    const float* n0b     = (const float*)d_in[6];
    const float* w0      = (const float*)d_in[7];
    const float* w1      = (const float*)d_in[8];
    const float* wout    = (const float*)d_in[9];
    const float* isw     = (const float*)d_in[10];
    const float* isb     = (const float*)d_in[11];
    const float* n1w     = (const float*)d_in[12];
    const float* n1b     = (const float*)d_in[13];
    const float* fc1w    = (const float*)d_in[14];
    const float* fc1b    = (const float*)d_in[15];
    const float* fc2w    = (const float*)d_in[16];
    const float* fc2b    = (const float*)d_in[17];
    const float* dec_w0  = (const float*)d_in[18];
    const float* dec_b0  = (const float*)d_in[19];
    const float* dec_w1  = (const float*)d_in[20];
    float* out = (float*)d_out;

    u16* ws = (u16*)d_ws;
    size_t off = 0;
    auto al = [&](size_t n){ u16* p = ws + off; off += (n + 63) & ~(size_t)63; return p; };
    u16* TWF = al(384*384);
    u16* TH  = al(2*384*384);           // THf, THi
    u16* TWI = al(384*360);
    u16* W0P = al((size_t)4*512*256);
    u16* W1P = al((size_t)4*512*512);
    u16* WOP = al((size_t)4*256*512);
    u16* ISWP= al((size_t)4*128*128);
    u16* FC1P= al((size_t)4*256*128);
    u16* FC2P= al((size_t)4*128*256);
    u16* EW1P= al(128*128);
    u16* DW0P= al(128*160);
    u16* XBF = al(2*HWSZ);
    u16* XN  = al((size_t)E_*HWSZ);
    u16* CUR = al((size_t)E_*HWSZ);
    u16* BIG = al((size_t)HID_*HWSZ);
    u16* SA  = al((size_t)23168*384);
    u16* ZC  = al((size_t)3*2965504);   // [z][2c+p][11584]
    u16* H1  = al((size_t)3*5931008);
    u16* H2  = al((size_t)3*5931008);

    dim3 blk(256);
    const int NB = 1<<30;
    const u16* np16 = nullptr;
    const float* npf = nullptr;

    // prepacks
    k_prep_twf<<<dim3((384*384+255)/256), blk, 0, stream>>>(TWF);
    k_prep_th <<<dim3((2*384*384+255)/256), blk, 0, stream>>>(TH);
    k_prep_twi<<<dim3((384*360+255)/256), blk, 0, stream>>>(TWI);
    for(int l=0;l<L_;l++){
        k_prep_cw<<<dim3((4*E_*HID_+255)/256), blk, 0, stream>>>(w0 + (size_t)l*2*E_*HID_, W0P + (size_t)l*512*256, E_, HID_);
        k_prep_cw<<<dim3((4*HID_*HID_+255)/256), blk, 0, stream>>>(w1 + (size_t)l*2*HID_*HID_, W1P + (size_t)l*512*512, HID_, HID_);
        k_prep_cw<<<dim3((4*HID_*E_+255)/256), blk, 0, stream>>>(wout + (size_t)l*2*HID_*E_, WOP + (size_t)l*256*512, HID_, E_);
        k_prep_w <<<dim3((128*128+255)/256), blk, 0, stream>>>(isw + (size_t)l*E_*E_, ISWP + (size_t)l*128*128, 128, 128, 128);
        k_prep_w <<<dim3((256*128+255)/256), blk, 0, stream>>>(fc1w + (size_t)l*HID_*E_, FC1P + (size_t)l*256*128, 256, 128, 128);
        k_prep_w <<<dim3((128*256+255)/256), blk, 0, stream>>>(fc2w + (size_t)l*E_*HID_, FC2P + (size_t)l*128*256, 128, 256, 256);
    }
    k_prep_w<<<dim3((128*128+255)/256), blk, 0, stream>>>(enc_w1, EW1P, 128, 128, 128);
    k_prep_w<<<dim3((128*160+255)/256), blk, 0, stream>>>(dec_w0, DW0P, 128, 130, 160);
    k_prep_w<<<dim3((2*HWSZ+255)/256), blk, 0, stream>>>(x, XBF, 2, HWSZ, HWSZ);

    auto G = [&](const u16* A,int lda, const u16* B1,const u16* B2,int K1,
                 long psB,long ldb2,int bshift,long bstr,int bnoffz,long bzstr,
                 u16* C,long psC,long ldc2,int cshift,long cstr,int cnoffz,long czstr,int cjmax,
                 const float* bias,const u16* addb,const float* addf,
                 int M,int N,int Kpad,int flags,int gz){
        dim3 g((N+127)/128, (M+127)/128, gz);
        k_gemm<<<g, blk, 0, stream>>>(A,lda,B1,B2,K1,psB,ldb2,bshift,bstr,bnoffz,bzstr,
            C,psC,ldc2,cshift,cstr,cnoffz,czstr,cjmax,bias,addb,addf,M,N,Kpad,flags);
    };

    // encoder
    k_enc0<<<dim3((E_*HWSZ+255)/256), blk, 0, stream>>>(x, enc_w0, enc_b0, BIG);
    G(EW1P,128, BIG,BIG,NB, HWSZ,2*HWSZ,30,0,0,0,
      CUR,HWSZ,2*HWSZ,30,0,0,0,NB, npf,np16,pos, 128,HWSZ,128, 0, 1);

    for(int l=0; l<L_; l++){
        k_inorm<<<dim3(E_), blk, 0, stream>>>(CUR, XN, n0w+l*E_, n0b+l*E_);
        // rdft: SA[r][384] = XN[r][360] x TWF
        G(XN,360, TWF,TWF,NB, 384,768,30,0,0,0,
          SA,384,768,30,0,0,0,NB, npf,np16,npf, 23168,384,384, 0, 1);
        // forward H-DFT (z=chunk): ZC = THf x SA-cols
        G(TH,384, SA,SA,NB, 192,384,6,69504,1,0,
          ZC,11584,64,6,23168,0,2965504,NB, npf,np16,npf, 362,8192,384, 0, 3);
        // cmix w0 (CReLU on even rows)
        G(W0P+(size_t)l*512*256,256, ZC,ZC,NB, 11584,23168,30,0,0,2965504,
          H1,11584,23168,30,0,0,5931008,NB, npf,np16,npf, 512,11584,256, 2|4, 3);
        // cmix w1
        G(W1P+(size_t)l*512*512,512, H1,H1,NB, 11584,23168,30,0,0,5931008,
          H2,11584,23168,30,0,0,5931008,NB, npf,np16,npf, 512,11584,512, 2|4, 3);
        // cmix wout
        G(WOP+(size_t)l*256*512,512, H2,H2,NB, 11584,23168,30,0,0,5931008,
          ZC,11584,23168,30,0,0,2965504,NB, npf,np16,npf, 256,11584,512, 0, 3);
        // inverse H-DFT: SA-cols = THi x ZC
        G(TH+384*384,384, ZC,ZC,NB, 11584,64,6,23168,0,2965504,
          SA,192,384,6,69504,1,0,181, npf,np16,npf, 362,8192,384, 0, 3);
        // irdft: CUR[r][360] = SA[r][384] x TWI
        G(SA,384, TWI,TWI,NB, 360,720,30,0,0,0,
          CUR,360,720,30,0,0,0,NB, npf,np16,npf, 23168,360,384, 0, 1);
        // inner skip: CUR = isw*XN + isb + CUR
        G(ISWP+(size_t)l*128*128,128, XN,XN,NB, HWSZ,2*HWSZ,30,0,0,0,
          CUR,HWSZ,2*HWSZ,30,0,0,0,NB, isb+l*E_,CUR,npf, 128,HWSZ,128, 0, 1);
        k_inorm<<<dim3(E_), blk, 0, stream>>>(CUR, CUR, n1w+l*E_, n1b+l*E_);
        // fc1 + gelu
        G(FC1P+(size_t)l*256*128,128, CUR,CUR,NB, HWSZ,2*HWSZ,30,0,0,0,
          BIG,HWSZ,2*HWSZ,30,0,0,0,NB, fc1b+l*HID_,np16,npf, 256,HWSZ,128, 1, 1);
        // fc2 + outer skip (XN)
        G(FC2P+(size_t)l*128*256,256, BIG,BIG,NB, HWSZ,2*HWSZ,30,0,0,0,
          CUR,HWSZ,2*HWSZ,30,0,0,0,NB, fc2b+l*E_,XN,npf, 128,HWSZ,256, 0, 1);
    }
    // decoder conv0 (concat CUR,x) + gelu
    G(DW0P,160, CUR,XBF,128, HWSZ,2*HWSZ,30,0,0,0,
      XN,HWSZ,2*HWSZ,30,0,0,0,NB, dec_b0,np16,npf, 128,HWSZ,160, 1, 1);
    k_dec1<<<dim3((HWSZ+255)/256), blk, 0, stream>>>(XN, dec_w1, out);
}

// Round 4
// 2485.108 us; speedup vs baseline: 2.7710x; 1.0137x over previous
//
#include <hip/hip_runtime.h>
#include <math.h>

#define NP 65160        // 181*360 points
#define NPAD 65280      // padded rows for 128-tiles
#define H_ 181
#define W_ 360

typedef unsigned short u16;
typedef __attribute__((ext_vector_type(8))) short bf16x8;
typedef __attribute__((ext_vector_type(8))) unsigned short us8;
typedef __attribute__((ext_vector_type(4))) float f32x4;

__device__ __forceinline__ u16 f2bf(float f){
    unsigned u = __builtin_bit_cast(unsigned, f);
    return (u16)((u + 0x7FFFu + ((u>>16)&1u)) >> 16);
}
__device__ __forceinline__ float bf2f(u16 h){
    unsigned u = ((unsigned)h)<<16;
    return __builtin_bit_cast(float, u);
}
__device__ __forceinline__ float gelu_f(float x){
    return 0.5f*x*(1.0f+erff(x*0.70710678118654752f));
}
__device__ __forceinline__ int div181(int m){   // exact for m < 2^31/181-ish
    return (int)(((unsigned long long)(unsigned)m * 759331235ull) >> 37);
}

// ============ zero ============
__global__ void k_zero(u16* __restrict__ p, int n){
    int i = (blockIdx.x*256 + threadIdx.x)*8;
    if(i+8 <= n){ us8 z = {0,0,0,0,0,0,0,0}; *(us8*)(p+i) = z; }
}

// ============ B packs ============
// all packs: dst[kg][n][e], k = kg*8+e, zero padded
__global__ void k_pack_twf2(u16* __restrict__ dst){ // KG=48,Npad=384: k=w, n=2kw+q
    int i = blockIdx.x*256+threadIdx.x; if(i >= 48*384*8) return;
    int e = i&7, n = (i>>3)%384, kg = i/(384*8);
    int k = kg*8+e, kw = n>>1, q = n&1;
    float v = 0.0f;
    if(k < 360 && n < 362){
        float inv = 1.0f/sqrtf((float)(H_*W_));
        float th = 6.28318530717958647692f*(float)((k*kw)%W_)/(float)W_;
        v = q ? -sinf(th)*inv : cosf(th)*inv;
    }
    dst[i] = f2bf(v);
}
__global__ void k_pack_th(u16* __restrict__ dst, int inverse){ // KG=48,Npad=384
    int i = blockIdx.x*256+threadIdx.x; if(i >= 48*384*8) return;
    int e = i&7, n = (i>>3)%384, kg = i/(384*8);
    int k = kg*8+e;
    float v = 0.0f;
    if(k < 362 && n < 362){
        int a = k>>1, qa = k&1, b = n>>1, pb = n&1;
        float th = 6.28318530717958647692f*(float)((a*b)%H_)/(float)H_;
        float c = cosf(th), s = sinf(th);
        if(!inverse) v = (pb==0) ? (qa==0? c :  s) : (qa==0? -s : c);
        else         v = (pb==0) ? (qa==0? c : -s) : (qa==0?  s : c);
    }
    dst[i] = f2bf(v);
}
__global__ void k_pack_twi2(u16* __restrict__ dst){ // KG=48,Npad=384: k=2kw+p, n=w
    int i = blockIdx.x*256+threadIdx.x; if(i >= 48*384*8) return;
    int e = i&7, n = (i>>3)%384, kg = i/(384*8);
    int k = kg*8+e, kw = k>>1, p = k&1;
    float v = 0.0f;
    if(k < 362 && n < 360){
        float inv = 1.0f/sqrtf((float)(H_*W_));
        float eps = (kw==0 || kw==180) ? 1.0f : 2.0f;
        float th = 6.28318530717958647692f*(float)((n*kw)%W_)/(float)W_;
        v = p ? -eps*sinf(th)*inv : eps*cosf(th)*inv;
    }
    dst[i] = f2bf(v);
}
__global__ void k_pack_cw(const float* __restrict__ src, u16* __restrict__ dst,
                          int CIN, int COUT, int lss, int lsd){
    int z = blockIdx.z;
    int Npad = 2*COUT, KG = (2*CIN)/8;
    int tot = KG*Npad*8;
    int i = blockIdx.x*256+threadIdx.x; if(i >= tot) return;
    int e = i&7, n = (i>>3)%Npad, kg = i/(Npad*8);
    int k = kg*8+e, ci = k>>1, q = k&1, co = n>>1, p = n&1;
    float re = src[(size_t)z*lss + ci*COUT + co];
    float im = src[(size_t)z*lss + CIN*COUT + ci*COUT + co];
    float v = (p==0) ? (q==0? re : -im) : (q==0? im : re);
    dst[(size_t)z*lsd + i] = f2bf(v);
}
__global__ void k_pack_rw(const float* __restrict__ src, u16* __restrict__ dst,
                          int Nn, int Ks, int KG, int lss, int lsd){
    int z = blockIdx.z;
    int tot = KG*Nn*8;
    int i = blockIdx.x*256+threadIdx.x; if(i >= tot) return;
    int e = i&7, n = (i>>3)%Nn, kg = i/(Nn*8);
    int k = kg*8+e;
    float v = (k < Ks) ? src[(size_t)z*lss + n*Ks + k] : 0.0f;
    dst[(size_t)z*lsd + i] = f2bf(v);
}

// ============ pointwise ============
__global__ void k_enc0(const float* __restrict__ x, const float* __restrict__ w,
                       const float* __restrict__ b, u16* __restrict__ out){
    int i = blockIdx.x*256+threadIdx.x;
    if(i >= NP*16) return;
    int p = i>>4, c8 = (i&15)*8;
    float x0 = x[p], x1 = x[NP+p];
    us8 o;
    #pragma unroll
    for(int j=0;j<8;j++){
        int e = c8+j;
        float v = w[e*2]*x0 + w[e*2+1]*x1 + b[e];
        o[j] = f2bf(gelu_f(v));
    }
    *(us8*)(out + (size_t)p*128 + c8) = o;
}
__global__ void k_xt2(const float* __restrict__ x, u16* __restrict__ dst){
    int p = blockIdx.x*256+threadIdx.x; if(p >= NP) return;
    us8 z = {0,0,0,0,0,0,0,0};
    z[0] = f2bf(x[p]); z[1] = f2bf(x[NP+p]);
    *(us8*)(dst + (size_t)p*32) = z;
    us8 z2 = {0,0,0,0,0,0,0,0};
    *(us8*)(dst + (size_t)p*32 + 8)  = z2;
    *(us8*)(dst + (size_t)p*32 + 16) = z2;
    *(us8*)(dst + (size_t)p*32 + 24) = z2;
}
__global__ void k_dec1(const u16* __restrict__ hid, const float* __restrict__ w,
                       float* __restrict__ out){
    int p = blockIdx.x*256+threadIdx.x; if(p >= NP) return;
    float a0=0.0f, a1=0.0f;
    #pragma unroll 4
    for(int k8=0;k8<16;k8++){
        us8 v = *(const us8*)(hid + (size_t)p*128 + k8*8);
        #pragma unroll
        for(int j=0;j<8;j++){
            float f = bf2f(v[j]);
            a0 = fmaf(w[k8*8+j], f, a0);
            a1 = fmaf(w[128+k8*8+j], f, a1);
        }
    }
    out[p] = a0; out[NP+p] = a1;
}

// ============ instance norm ============
__global__ __launch_bounds__(256) void k_istat(const u16* __restrict__ X, float* __restrict__ stat){
    int t = threadIdx.x;
    int c8 = (t&15)*8;
    float s[8], s2[8];
    #pragma unroll
    for(int j=0;j<8;j++){ s[j]=0.0f; s2[j]=0.0f; }
    for(int p = blockIdx.x*16 + (t>>4); p < NP; p += gridDim.x*16){
        us8 v = *(const us8*)(X + (size_t)p*128 + c8);
        #pragma unroll
        for(int j=0;j<8;j++){ float f = bf2f(v[j]); s[j]+=f; s2[j]=fmaf(f,f,s2[j]); }
    }
    __shared__ float L[256][8];
    #pragma unroll
    for(int j=0;j<8;j++) L[t][j]=s[j];
    __syncthreads();
    for(int st=128; st>=16; st>>=1){
        if(t<st){ 
            #pragma unroll
            for(int j=0;j<8;j++) L[t][j]+=L[t+st][j];
        }
        __syncthreads();
    }
    if(t<16){ 
        #pragma unroll
        for(int j=0;j<8;j++) atomicAdd(&stat[t*8+j], L[t][j]);
    }
    __syncthreads();
    #pragma unroll
    for(int j=0;j<8;j++) L[t][j]=s2[j];
    __syncthreads();
    for(int st=128; st>=16; st>>=1){
        if(t<st){
            #pragma unroll
            for(int j=0;j<8;j++) L[t][j]+=L[t+st][j];
        }
        __syncthreads();
    }
    if(t<16){
        #pragma unroll
        for(int j=0;j<8;j++) atomicAdd(&stat[128+t*8+j], L[t][j]);
    }
}
// apply norm, write pm; optionally also write cm (transposed) via LDS
__global__ __launch_bounds__(256) void k_apply_t(
    const u16* __restrict__ X, u16* __restrict__ outp, u16* __restrict__ outc,
    const float* __restrict__ stat, const float* __restrict__ gw, const float* __restrict__ gb)
{
    __shared__ u16 T[128][72];
    __shared__ float SA_[128], SB_[128];
    int t = threadIdx.x;
    if(t < 128){
        float mu = stat[t]*(1.0f/(float)NP);
        float var = stat[128+t]*(1.0f/(float)NP) - mu*mu;
        var = fmaxf(var, 0.0f);
        float rstd = 1.0f/sqrtf(var + 1e-6f);
        float a = rstd*gw[t];
        SA_[t] = a; SB_[t] = gb[t] - mu*a;
    }
    __syncthreads();
    int p0 = blockIdx.x*64;
    int pl = t>>2, cc = (t&3)*32;
    int p = p0 + pl;
    if(p < NP){
        #pragma unroll
        for(int jj=0;jj<4;jj++){
            us8 v = *(const us8*)(X + (size_t)p*128 + cc + jj*8);
            us8 o;
            #pragma unroll
            for(int j=0;j<8;j++){
                int c = cc + jj*8 + j;
                o[j] = f2bf(fmaf(bf2f(v[j]), SA_[c], SB_[c]));
            }
            *(us8*)(outp + (size_t)p*128 + cc + jj*8) = o;
            #pragma unroll
            for(int j=0;j<8;j++) T[cc+jj*8+j][pl] = o[j];
        }
    }
    __syncthreads();
    int c = t>>1, half = t&1;
    int pbase = p0 + half*32;
    #pragma unroll
    for(int jj=0;jj<4;jj++){
        int pp = pbase + jj*8;
        if(pp + 8 <= NP){
            *(us8*)(outc + (size_t)c*NP + pp) = *(const us8*)(&T[c][half*32 + jj*8]);
        }
    }
}
__global__ __launch_bounds__(256) void k_apply(
    const u16* __restrict__ X, u16* __restrict__ outp,
    const float* __restrict__ stat, const float* __restrict__ gw, const float* __restrict__ gb)
{
    __shared__ float SA_[128], SB_[128];
    int t = threadIdx.x;
    if(t < 128){
        float mu = stat[t]*(1.0f/(float)NP);
        float var = stat[128+t]*(1.0f/(float)NP) - mu*mu;
        var = fmaxf(var, 0.0f);
        float rstd = 1.0f/sqrtf(var + 1e-6f);
        float a = rstd*gw[t];
        SA_[t] = a; SB_[t] = gb[t] - mu*a;
    }
    __syncthreads();
    int i = blockIdx.x*256 + t;
    if(i >= NP*16) return;
    int p = i>>4, c8 = (i&15)*8;
    us8 v = *(const us8*)(X + (size_t)p*128 + c8);
    us8 o;
    #pragma unroll
    for(int j=0;j<8;j++) o[j] = f2bf(fmaf(bf2f(v[j]), SA_[c8+j], SB_[c8+j]));
    *(us8*)(outp + (size_t)p*128 + c8) = o;
}

// ============ transposes ============
// cm [128][NP] bf16 -> pm [NPAD][128] bf16
__global__ __launch_bounds__(256) void k_tr(const u16* __restrict__ src, u16* __restrict__ dst){
    __shared__ u16 T[128][72];
    int t = threadIdx.x;
    int p0 = blockIdx.x*64;
    int c = t>>1, half = t&1;
    int pbase = p0 + half*32;
    #pragma unroll
    for(int jj=0;jj<4;jj++){
        int pp = pbase + jj*8;
        us8 v = {0,0,0,0,0,0,0,0};
        if(pp + 8 <= NP) v = *(const us8*)(src + (size_t)c*NP + pp);
        *(us8*)(&T[c][half*32 + jj*8]) = v;
    }
    __syncthreads();
    int pl = t>>2, cc = (t&3)*32;
    int p = p0 + pl;
    if(p < NP){
        #pragma unroll
        for(int jj=0;jj<4;jj++){
            us8 o;
            #pragma unroll
            for(int j=0;j<8;j++) o[j] = T[cc+jj*8+j][pl];
            *(us8*)(dst + (size_t)p*128 + cc + jj*8) = o;
        }
    }
}
// pos f32 cm [128][NP] -> bf16 pm [NPAD][128]
__global__ __launch_bounds__(256) void k_post(const float* __restrict__ src, u16* __restrict__ dst){
    __shared__ u16 T[128][72];
    int t = threadIdx.x;
    int p0 = blockIdx.x*64;
    int c = t>>1, half = t&1;
    int pbase = p0 + half*32;
    #pragma unroll
    for(int jj=0;jj<4;jj++){
        int pp = pbase + jj*8;
        us8 v = {0,0,0,0,0,0,0,0};
        if(pp + 8 <= NP){
            #pragma unroll
            for(int j=0;j<8;j++) v[j] = f2bf(src[(size_t)c*NP + pp + j]);
        }
        *(us8*)(&T[c][half*32 + jj*8]) = v;
    }
    __syncthreads();
    int pl = t>>2, cc = (t&3)*32;
    int p = p0 + pl;
    if(p < NP){
        #pragma unroll
        for(int jj=0;jj<4;jj++){
            us8 o;
            #pragma unroll
            for(int j=0;j<8;j++) o[j] = T[cc+jj*8+j][pl];
            *(us8*)(dst + (size_t)p*128 + cc + jj*8) = o;
        }
    }
}

// ============ generic MFMA GEMM ============
// C[m][n] = sum_k A[m][k]*B[k][n];  A k-contig; B prepacked [k/8][n][8]
// C addr = cmC*cstr1 + cmH*cstr2 + (n>>cnsh)*cstr3 + (n&cnmask)*cstr4
//   cdiv181: cmC=m/181, cmH=m%181  else cmC=m>>cmsh, cmH=m&cmmask
// flags: 1=gelu, 2=relu on even n
__global__ __launch_bounds__(256) void k_gemm(
    const u16* __restrict__ A1, const u16* __restrict__ A2, int aksplit, int astr, int a2str,
    const u16* __restrict__ B, int bkstr,
    u16* __restrict__ C,
    int cdiv181, int cmsh, int cmmask,
    int cstr1, int cstr2, int cnsh, int cnmask, int cstr3, int cstr4,
    int cmhmax,
    const float* __restrict__ bias, const u16* __restrict__ addb,
    int Mvalid, int N, int Kpad, int flags)
{
    int tid = threadIdx.x;
    int l = tid & 63, wv = tid >> 6;
    int wm = wv >> 1, wn = wv & 1;
    int lm = l & 15, kgl = l >> 4;
    int m0 = blockIdx.y*128 + wm*64;
    int n0 = blockIdx.x*128 + wn*64;

    int ab1[4], ab2[4];
    #pragma unroll
    for(int i2=0;i2<4;i2++){
        int mi = m0 + i2*16 + lm;
        ab1[i2] = mi*astr;
        ab2[i2] = mi*a2str;
    }
    int bn[4];
    #pragma unroll
    for(int j2=0;j2<4;j2++) bn[j2] = (n0 + j2*16 + lm)*8;

    f32x4 acc[4][4];
    #pragma unroll
    for(int i2=0;i2<4;i2++)
        #pragma unroll
        for(int j2=0;j2<4;j2++)
            acc[i2][j2] = (f32x4){0.0f,0.0f,0.0f,0.0f};

    for(int k0=0; k0<Kpad; k0+=32){
        int kk = k0 + kgl*8;
        bool s1 = kk < aksplit;
        const u16* Ab = s1 ? A1 : A2;
        int kof = s1 ? kk : kk - aksplit;
        bf16x8 af[4];
        #pragma unroll
        for(int i2=0;i2<4;i2++)
            af[i2] = *(const bf16x8*)(Ab + (s1 ? ab1[i2] : ab2[i2]) + kof);
        const u16* Bb = B + (size_t)((k0>>3) + kgl)*bkstr;
        bf16x8 bf[4];
        #pragma unroll
        for(int j2=0;j2<4;j2++)
            bf[j2] = *(const bf16x8*)(Bb + bn[j2]);
        #pragma unroll
        for(int i2=0;i2<4;i2++)
            #pragma unroll
            for(int j2=0;j2<4;j2++)
                acc[i2][j2] = __builtin_amdgcn_mfma_f32_16x16x32_bf16(af[i2], bf[j2], acc[i2][j2], 0,0,0);
    }

    #pragma unroll
    for(int i2=0;i2<4;i2++){
        #pragma unroll
        for(int r=0;r<4;r++){
            int m = m0 + i2*16 + kgl*4 + r;
            if(m >= Mvalid) continue;
            int cmC, cmH;
            if(cdiv181){ cmC = div181(m); cmH = m - cmC*181; }
            else { cmC = m >> cmsh; cmH = m & cmmask; }
            if(cmH >= cmhmax) continue;
            int mbase = cmC*cstr1 + cmH*cstr2;
            #pragma unroll
            for(int j2=0;j2<4;j2++){
                int n = n0 + j2*16 + lm;
                if(n >= N) continue;
                int caddr = mbase + (n>>cnsh)*cstr3 + (n&cnmask)*cstr4;
                float v = acc[i2][j2][r];
                if(bias) v += bias[n];
                if(flags & 1) v = gelu_f(v);
                if((flags & 2) && ((n&1)==0)) v = fmaxf(v, 0.0f);
                if(addb) v += bf2f(addb[caddr]);
                C[caddr] = f2bf(v);
            }
        }
    }
}

// ============ launch ============
extern "C" void kernel_launch(void* const* d_in, const int* in_sizes, int n_in,
                              void* d_out, int out_size, void* d_ws, size_t ws_size,
                              hipStream_t stream) {
    const float* x       = (const float*)d_in[0];
    const float* enc_w0  = (const float*)d_in[1];
    const float* enc_b0  = (const float*)d_in[2];
    const float* enc_w1  = (const float*)d_in[3];
    const float* pos     = (const float*)d_in[4];
    const float* n0w     = (const float*)d_in[5];
    const float* n0b     = (const float*)d_in[6];
    const float* w0      = (const float*)d_in[7];
    const float* w1      = (const float*)d_in[8];
    const float* wout    = (const float*)d_in[9];
    const float* isw     = (const float*)d_in[10];
    const float* isb     = (const float*)d_in[11];
    const float* n1w     = (const float*)d_in[12];
    const float* n1b     = (const float*)d_in[13];
    const float* fc1w    = (const float*)d_in[14];
    const float* fc1b    = (const float*)d_in[15];
    const float* fc2w    = (const float*)d_in[16];
    const float* fc2b    = (const float*)d_in[17];
    const float* dec_w0  = (const float*)d_in[18];
    const float* dec_b0  = (const float*)d_in[19];
    const float* dec_w1  = (const float*)d_in[20];
    float* out = (float*)d_out;

    u16* ws = (u16*)d_ws;
    size_t off = 0;
    auto al = [&](size_t n){ u16* p = ws + off; off += (n + 63) & ~(size_t)63; return p; };
    u16* TWF2 = al(147456);
    u16* THFB = al(147456);
    u16* THIB = al(147456);
    u16* TWI2 = al(147456);
    u16* W0P  = al(524288);
    u16* W1P  = al(1048576);
    u16* WOP  = al(524288);
    u16* ISWP = al(65536);
    u16* FC1P = al(131072);
    u16* FC2P = al(131072);
    u16* EW1P = al(16384);
    u16* DW0P = al(20480);
    u16* POSP = al((size_t)NPAD*128);
    u16* XT2  = al((size_t)NPAD*32);
    u16* CURP = al((size_t)NPAD*128);
    u16* XNP  = al((size_t)NPAD*128);
    u16* YP   = al((size_t)NPAD*128);
    u16* XNC  = al((size_t)128*NP + 768);
    u16* SA2  = al((size_t)32768*384);       // also Z4
    u16* Z3   = al((size_t)32768*256);       // also Y_cm
    u16* H1   = al((size_t)32768*512);       // also ENC_pm
    u16* H2   = al((size_t)32768*512);       // also BIG_pm
    u16* SB   = al((size_t)23168*384);
    u16* IST  = al(4096);                     // 8 x 256 f32
    float* ISTAT = (float*)IST;
    u16* ENC = H1;
    u16* BIG = H2;
    u16* Z4  = SA2;
    u16* YC  = Z3;

    dim3 blk(256);
    auto gz = [&](u16* p, int n){ k_zero<<<dim3((n/8+255)/256), blk, 0, stream>>>(p, n); };
    gz(SA2, 32768*384);
    gz(SB, 23168*384);
    gz(XNC + (size_t)128*NP, 768);
    gz(IST, 4096);

    // packs
    k_pack_twf2<<<dim3((48*384*8+255)/256), blk, 0, stream>>>(TWF2);
    k_pack_th  <<<dim3((48*384*8+255)/256), blk, 0, stream>>>(THFB, 0);
    k_pack_th  <<<dim3((48*384*8+255)/256), blk, 0, stream>>>(THIB, 1);
    k_pack_twi2<<<dim3((48*384*8+255)/256), blk, 0, stream>>>(TWI2);
    k_pack_cw<<<dim3((131072+255)/256,1,4), blk, 0, stream>>>(w0,   W0P, 128, 256, 2*128*256, 131072);
    k_pack_cw<<<dim3((262144+255)/256,1,4), blk, 0, stream>>>(w1,   W1P, 256, 256, 2*256*256, 262144);
    k_pack_cw<<<dim3((131072+255)/256,1,4), blk, 0, stream>>>(wout, WOP, 256, 128, 2*256*128, 131072);
    k_pack_rw<<<dim3((16384+255)/256,1,4),  blk, 0, stream>>>(isw,  ISWP, 128, 128, 16, 128*128, 16384);
    k_pack_rw<<<dim3((32768+255)/256,1,4),  blk, 0, stream>>>(fc1w, FC1P, 256, 128, 16, 256*128, 32768);
    k_pack_rw<<<dim3((32768+255)/256,1,4),  blk, 0, stream>>>(fc2w, FC2P, 128, 256, 32, 128*256, 32768);
    k_pack_rw<<<dim3((16384+255)/256,1,1),  blk, 0, stream>>>(enc_w1, EW1P, 128, 128, 16, 0, 0);
    k_pack_rw<<<dim3((20480+255)/256,1,1),  blk, 0, stream>>>(dec_w0, DW0P, 128, 130, 20, 0, 0);
    k_post<<<dim3(1019), blk, 0, stream>>>(pos, POSP);
    k_xt2 <<<dim3((NP+255)/256), blk, 0, stream>>>(x, XT2);

    const u16* nu = nullptr;
    const float* nf = nullptr;
    auto G = [&](const u16* A1v, const u16* A2v, int aksplit, int astr, int a2str,
                 const u16* Bv, int bkstr, u16* Cv,
                 int cdiv181, int cmsh, int cmmask, int cstr1, int cstr2,
                 int cnsh, int cnmask, int cstr3, int cstr4, int cmhmax,
                 const float* bias, const u16* addb,
                 int Mgrid, int Mvalid, int N, int Kpad, int flags){
        dim3 g((N+127)/128, (Mgrid+127)/128, 1);
        k_gemm<<<g, blk, 0, stream>>>(A1v, A2v, aksplit, astr, a2str, Bv, bkstr, Cv,
            cdiv181, cmsh, cmmask, cstr1, cstr2, cnsh, cnmask, cstr3, cstr4, cmhmax,
            bias, addb, Mvalid, N, Kpad, flags);
    };
    const int BIGV = 1<<28;

    // encoder
    k_enc0<<<dim3((NP*16+255)/256), blk, 0, stream>>>(x, enc_w0, enc_b0, ENC);
    G(ENC, ENC, BIGV, 128, 128, EW1P, 1024, CURP,
      0,0,0, 128,0, 0,0, 1,0, BIGV, nf, POSP, NP, NP, 128, 128, 0);

    for(int l=0; l<4; l++){
        float* st0 = ISTAT + (2*l)*256;
        float* st1 = ISTAT + (2*l+1)*256;
        // norm0 (+transposed copy)
        k_istat<<<dim3(128), blk, 0, stream>>>(CURP, st0);
        k_apply_t<<<dim3(1019), blk, 0, stream>>>(CURP, XNP, XNC, st0, n0w+l*128, n0b+l*128);
        // rdft: SA2[(c*256+kw)*384 + 2h+q] from XNC rows m=c*181+h
        G(XNC, XNC, BIGV, 360, 360, TWF2, 3072, SA2,
          1,0,0, 98304,2, 1,1, 384,1, BIGV, nf, nu, 23168, 23168, 362, 384, 0);
        // H-DFT fwd: Z3[pt*256 + 2c+p] from SA2 rows m=c*256+kw
        G(SA2, SA2, BIGV, 384, 384, THFB, 3072, Z3,
          0,8,255, 2,256, 1,1, 46336,1, 181, nf, nu, 32768, 32768, 362, 384, 0);
        // cmix w0 -> H1 [pt][512], CReLU on even n
        G(Z3, Z3, BIGV, 256, 256, W0P + (size_t)l*131072, 4096, H1,
          0,0,0, 512,0, 0,0, 1,0, BIGV, nf, nu, 32768, 32761, 512, 256, 2);
        // cmix w1 -> H2
        G(H1, H1, BIGV, 512, 512, W1P + (size_t)l*262144, 4096, H2,
          0,0,0, 512,0, 0,0, 1,0, BIGV, nf, nu, 32768, 32761, 512, 512, 2);
        // cmix wout -> Z4 [(c*256+kw)*384 + 2kh+p]
        G(H2, H2, BIGV, 512, 512, WOP + (size_t)l*131072, 2048, Z4,
          1,0,0, 2,384, 1,1, 98304,1, BIGV, nf, nu, 32768, 32761, 256, 512, 0);
        // iH-DFT: SB[(c*181+h)*384 + 2kw+p] from Z4 rows m=c*256+kw
        G(Z4, Z4, BIGV, 384, 384, THIB, 3072, SB,
          0,8,255, 69504,2, 1,1, 384,1, 181, nf, nu, 32768, 32768, 362, 384, 0);
        // irdft: YC[m*360 + w] from SB rows m=c*181+h
        G(SB, SB, BIGV, 384, 384, TWI2, 3072, YC,
          0,0,0, 360,0, 0,0, 1,0, BIGV, nf, nu, 23168, 23168, 360, 384, 0);
        // transpose YC (cm) -> YP (pm)
        k_tr<<<dim3(1019), blk, 0, stream>>>(YC, YP);
        // inner skip: CUR = isw*XN + isb + Y
        G(XNP, XNP, BIGV, 128, 128, ISWP + (size_t)l*16384, 1024, CURP,
          0,0,0, 128,0, 0,0, 1,0, BIGV, isb+l*128, YP, NP, NP, 128, 128, 0);
        // norm1
        k_istat<<<dim3(128), blk, 0, stream>>>(CURP, st1);
        k_apply<<<dim3((NP*16+255)/256), blk, 0, stream>>>(CURP, YP, st1, n1w+l*128, n1b+l*128);
        // fc1 + gelu -> BIG [p][256]
        G(YP, YP, BIGV, 128, 128, FC1P + (size_t)l*32768, 2048, BIG,
          0,0,0, 256,0, 0,0, 1,0, BIGV, fc1b+l*256, nu, NP, NP, 256, 128, 1);
        // fc2 + outer skip(XN) -> CUR
        G(BIG, BIG, BIGV, 256, 256, FC2P + (size_t)l*32768, 1024, CURP,
          0,0,0, 128,0, 0,0, 1,0, BIGV, fc2b+l*128, XNP, NP, NP, 128, 256, 0);
    }
    // decoder conv0: gelu(dec_w0 * [CUR ; x]) -> XNP
    G(CURP, XT2, 128, 128, 32, DW0P, 1024, XNP,
      0,0,0, 128,0, 0,0, 1,0, BIGV, dec_b0, nu, NP, NP, 128, 160, 1);
    k_dec1<<<dim3((NP+255)/256), blk, 0, stream>>>(XNP, dec_w1, out);
}

// Round 5
// 2115.016 us; speedup vs baseline: 3.2559x; 1.1750x over previous
//
#include <hip/hip_runtime.h>
#include <math.h>

#define NP 65160        // 181*360
#define NPAD 65280

typedef unsigned short u16;
typedef __attribute__((ext_vector_type(8))) short bf16x8;
typedef __attribute__((ext_vector_type(8))) unsigned short us8;
typedef __attribute__((ext_vector_type(4))) float f32x4;

__device__ __forceinline__ u16 f2bf(float f){
    unsigned u = __builtin_bit_cast(unsigned, f);
    return (u16)((u + 0x7FFFu + ((u>>16)&1u)) >> 16);
}
__device__ __forceinline__ float bf2f(u16 h){
    unsigned u = ((unsigned)h)<<16;
    return __builtin_bit_cast(float, u);
}
__device__ __forceinline__ float gelu_f(float x){
    return 0.5f*x*(1.0f+erff(x*0.70710678118654752f));
}

__global__ void k_zero(u16* __restrict__ p, long n){
    long i = ((long)blockIdx.x*256 + threadIdx.x)*8;
    if(i+8 <= n){ us8 z = {0,0,0,0,0,0,0,0}; *(us8*)(p+i) = z; }
}

// ============ B packs: dst[kg][n][8], k = kg*8+e, zero padded ============
// TWF [48][384][8]: k=w, n=2kw+q
__global__ void k_pack_twf(u16* __restrict__ dst){
    int i = blockIdx.x*256+threadIdx.x; if(i >= 48*384*8) return;
    int e = i&7, n = (i>>3)%384, kg = i/(384*8);
    int k = kg*8+e, kw = n>>1, q = n&1;
    float v = 0.0f;
    if(k < 360 && kw < 181){
        float inv = 1.0f/sqrtf(65160.0f);
        float th = 6.28318530717958647692f*(float)((k*kw)%360)/360.0f;
        v = q ? -sinf(th)*inv : cosf(th)*inv;
    }
    dst[i] = f2bf(v);
}
// THF [64][384][8]: k=2h+q, n=2kh+p
__global__ void k_pack_thf(u16* __restrict__ dst){
    int i = blockIdx.x*256+threadIdx.x; if(i >= 64*384*8) return;
    int e = i&7, n = (i>>3)%384, kg = i/(384*8);
    int k = kg*8+e;
    float v = 0.0f;
    if(k < 362 && n < 362){
        int h = k>>1, q = k&1, kh = n>>1, p = n&1;
        float th = 6.28318530717958647692f*(float)((h*kh)%181)/181.0f;
        float c = cosf(th), s = sinf(th);
        v = (q==0) ? (p==0? c : -s) : (p==0? s : c);
    }
    dst[i] = f2bf(v);
}
// THI [48][512][8]: k=2kh+p, n=2h+q  (same parity formula: rotation transpose = inverse)
__global__ void k_pack_thi(u16* __restrict__ dst){
    int i = blockIdx.x*256+threadIdx.x; if(i >= 48*512*8) return;
    int e = i&7, n = (i>>3)%512, kg = i/(512*8);
    int k = kg*8+e;
    float v = 0.0f;
    if(k < 362 && n < 362){
        int kh = k>>1, p = k&1, h = n>>1, q = n&1;
        float th = 6.28318530717958647692f*(float)((kh*h)%181)/181.0f;
        float c = cosf(th), s = sinf(th);
        v = (q==0) ? (p==0? c : -s) : (p==0? s : c);
    }
    dst[i] = f2bf(v);
}
// TWI [48][384][8]: k=2kw+q, n=w
__global__ void k_pack_twi(u16* __restrict__ dst){
    int i = blockIdx.x*256+threadIdx.x; if(i >= 48*384*8) return;
    int e = i&7, n = (i>>3)%384, kg = i/(384*8);
    int k = kg*8+e, kw = k>>1, q = k&1;
    float v = 0.0f;
    if(k < 362 && n < 360){
        float inv = 1.0f/sqrtf(65160.0f);
        float eps = (kw==0 || kw==180) ? 1.0f : 2.0f;
        float th = 6.28318530717958647692f*(float)((n*kw)%360)/360.0f;
        v = q ? -eps*sinf(th)*inv : eps*cosf(th)*inv;
    }
    dst[i] = f2bf(v);
}
__global__ void k_pack_cw(const float* __restrict__ src, u16* __restrict__ dst,
                          int CIN, int COUT, int lss, int lsd){
    int z = blockIdx.z;
    int Npad = 2*COUT, KG = (2*CIN)/8;
    int tot = KG*Npad*8;
    int i = blockIdx.x*256+threadIdx.x; if(i >= tot) return;
    int e = i&7, n = (i>>3)%Npad, kg = i/(Npad*8);
    int k = kg*8+e, ci = k>>1, q = k&1, co = n>>1, p = n&1;
    float re = src[(size_t)z*lss + ci*COUT + co];
    float im = src[(size_t)z*lss + CIN*COUT + ci*COUT + co];
    float v = (p==0) ? (q==0? re : -im) : (q==0? im : re);
    dst[(size_t)z*lsd + i] = f2bf(v);
}
__global__ void k_pack_rw(const float* __restrict__ src, u16* __restrict__ dst,
                          int Nn, int Ks, int KG, int lss, int lsd){
    int z = blockIdx.z;
    int tot = KG*Nn*8;
    int i = blockIdx.x*256+threadIdx.x; if(i >= tot) return;
    int e = i&7, n = (i>>3)%Nn, kg = i/(Nn*8);
    int k = kg*8+e;
    float v = (k < Ks) ? src[(size_t)z*lss + n*Ks + k] : 0.0f;
    dst[(size_t)z*lsd + i] = f2bf(v);
}

// ============ pointwise ============
__global__ void k_enc0(const float* __restrict__ x, const float* __restrict__ w,
                       const float* __restrict__ b, u16* __restrict__ out){
    int i = blockIdx.x*256+threadIdx.x;
    if(i >= NP*16) return;
    int p = i>>4, c8 = (i&15)*8;
    float x0 = x[p], x1 = x[NP+p];
    us8 o;
    #pragma unroll
    for(int j=0;j<8;j++){
        int e = c8+j;
        float v = w[e*2]*x0 + w[e*2+1]*x1 + b[e];
        o[j] = f2bf(gelu_f(v));
    }
    *(us8*)(out + (size_t)p*128 + c8) = o;
}
__global__ void k_xt2(const float* __restrict__ x, u16* __restrict__ dst){
    int p = blockIdx.x*256+threadIdx.x; if(p >= NP) return;
    us8 z = {0,0,0,0,0,0,0,0};
    z[0] = f2bf(x[p]); z[1] = f2bf(x[NP+p]);
    *(us8*)(dst + (size_t)p*32) = z;
    us8 z2 = {0,0,0,0,0,0,0,0};
    *(us8*)(dst + (size_t)p*32 + 8)  = z2;
    *(us8*)(dst + (size_t)p*32 + 16) = z2;
    *(us8*)(dst + (size_t)p*32 + 24) = z2;
}
__global__ void k_dec1(const u16* __restrict__ hid, const float* __restrict__ w,
                       float* __restrict__ out){
    int p = blockIdx.x*256+threadIdx.x; if(p >= NP) return;
    float a0=0.0f, a1=0.0f;
    #pragma unroll 4
    for(int k8=0;k8<16;k8++){
        us8 v = *(const us8*)(hid + (size_t)p*128 + k8*8);
        #pragma unroll
        for(int j=0;j<8;j++){
            float f = bf2f(v[j]);
            a0 = fmaf(w[k8*8+j], f, a0);
            a1 = fmaf(w[128+k8*8+j], f, a1);
        }
    }
    out[p] = a0; out[NP+p] = a1;
}

// ============ instance norm ============
__global__ __launch_bounds__(256) void k_istat(const u16* __restrict__ X, float* __restrict__ stat){
    int t = threadIdx.x;
    int c8 = (t&15)*8;
    float s[8], s2[8];
    #pragma unroll
    for(int j=0;j<8;j++){ s[j]=0.0f; s2[j]=0.0f; }
    for(int p = blockIdx.x*16 + (t>>4); p < NP; p += gridDim.x*16){
        us8 v = *(const us8*)(X + (size_t)p*128 + c8);
        #pragma unroll
        for(int j=0;j<8;j++){ float f = bf2f(v[j]); s[j]+=f; s2[j]=fmaf(f,f,s2[j]); }
    }
    __shared__ float L[256][8];
    #pragma unroll
    for(int j=0;j<8;j++) L[t][j]=s[j];
    __syncthreads();
    for(int st=128; st>=16; st>>=1){
        if(t<st){
            #pragma unroll
            for(int j=0;j<8;j++) L[t][j]+=L[t+st][j];
        }
        __syncthreads();
    }
    if(t<16){
        #pragma unroll
        for(int j=0;j<8;j++) atomicAdd(&stat[t*8+j], L[t][j]);
    }
    __syncthreads();
    #pragma unroll
    for(int j=0;j<8;j++) L[t][j]=s2[j];
    __syncthreads();
    for(int st=128; st>=16; st>>=1){
        if(t<st){
            #pragma unroll
            for(int j=0;j<8;j++) L[t][j]+=L[t+st][j];
        }
        __syncthreads();
    }
    if(t<16){
        #pragma unroll
        for(int j=0;j<8;j++) atomicAdd(&stat[128+t*8+j], L[t][j]);
    }
}
// apply norm -> point-major XNP; also channel-major XNC[(c*256+h)*384 + w]
__global__ __launch_bounds__(256) void k_apply_t(
    const u16* __restrict__ X, u16* __restrict__ outp, u16* __restrict__ outc,
    const float* __restrict__ stat, const float* __restrict__ gw, const float* __restrict__ gb)
{
    __shared__ u16 T[128][72];
    __shared__ float SA_[128], SB_[128];
    int t = threadIdx.x;
    if(t < 128){
        float mu = stat[t]*(1.0f/(float)NP);
        float var = stat[128+t]*(1.0f/(float)NP) - mu*mu;
        var = fmaxf(var, 0.0f);
        float rstd = 1.0f/sqrtf(var + 1e-6f);
        float a = rstd*gw[t];
        SA_[t] = a; SB_[t] = gb[t] - mu*a;
    }
    __syncthreads();
    int p0 = blockIdx.x*64;
    int pl = t>>2, cc = (t&3)*32;
    int p = p0 + pl;
    if(p < NP){
        #pragma unroll
        for(int jj=0;jj<4;jj++){
            us8 v = *(const us8*)(X + (size_t)p*128 + cc + jj*8);
            us8 o;
            #pragma unroll
            for(int j=0;j<8;j++){
                int c = cc + jj*8 + j;
                o[j] = f2bf(fmaf(bf2f(v[j]), SA_[c], SB_[c]));
            }
            *(us8*)(outp + (size_t)p*128 + cc + jj*8) = o;
            #pragma unroll
            for(int j=0;j<8;j++) T[cc+jj*8+j][pl] = o[j];
        }
    }
    __syncthreads();
    int c = t>>1, half = t&1;
    int pbase = p0 + half*32;
    #pragma unroll
    for(int jj=0;jj<4;jj++){
        int pp = pbase + jj*8;
        if(pp + 8 <= NP){
            int hh = pp/360, ww = pp - hh*360;   // 360%8==0 -> group stays in one row
            *(us8*)(outc + ((size_t)c*256 + hh)*384 + ww) = *(const us8*)(&T[c][half*32 + jj*8]);
        }
    }
}
__global__ __launch_bounds__(256) void k_apply(
    const u16* __restrict__ X, u16* __restrict__ outp,
    const float* __restrict__ stat, const float* __restrict__ gw, const float* __restrict__ gb)
{
    __shared__ float SA_[128], SB_[128];
    int t = threadIdx.x;
    if(t < 128){
        float mu = stat[t]*(1.0f/(float)NP);
        float var = stat[128+t]*(1.0f/(float)NP) - mu*mu;
        var = fmaxf(var, 0.0f);
        float rstd = 1.0f/sqrtf(var + 1e-6f);
        float a = rstd*gw[t];
        SA_[t] = a; SB_[t] = gb[t] - mu*a;
    }
    __syncthreads();
    int i = blockIdx.x*256 + t;
    if(i >= NP*16) return;
    int p = i>>4, c8 = (i&15)*8;
    us8 v = *(const us8*)(X + (size_t)p*128 + c8);
    us8 o;
    #pragma unroll
    for(int j=0;j<8;j++) o[j] = f2bf(fmaf(bf2f(v[j]), SA_[c8+j], SB_[c8+j]));
    *(us8*)(outp + (size_t)p*128 + c8) = o;
}
// pos f32 [128][NP] -> bf16 [pt][128]
__global__ __launch_bounds__(256) void k_post(const float* __restrict__ src, u16* __restrict__ dst){
    __shared__ u16 T[128][72];
    int t = threadIdx.x;
    int p0 = blockIdx.x*64;
    int c = t>>1, half = t&1;
    int pbase = p0 + half*32;
    #pragma unroll
    for(int jj=0;jj<4;jj++){
        int pp = pbase + jj*8;
        us8 v = {0,0,0,0,0,0,0,0};
        if(pp + 8 <= NP){
            #pragma unroll
            for(int j=0;j<8;j++) v[j] = f2bf(src[(size_t)c*NP + pp + j]);
        }
        *(us8*)(&T[c][half*32 + jj*8]) = v;
    }
    __syncthreads();
    int pl = t>>2, cc = (t&3)*32;
    int p = p0 + pl;
    if(p < NP){
        #pragma unroll
        for(int jj=0;jj<4;jj++){
            us8 o;
            #pragma unroll
            for(int j=0;j<8;j++) o[j] = T[cc+jj*8+j][pl];
            *(us8*)(dst + (size_t)p*128 + cc + jj*8) = o;
        }
    }
}

// ============ MFMA GEMM with coalescing transpose-store epilogue ============
// tmode 0: C[m*cstr + n] (masks, bias/gelu/relu-even/addb)
// tmode 1: m=c*256+h,  n=2kw+q -> C[(kw*128+c)*512 + 2h+q]      (S1)
// tmode 2: m=kw*128+c, n=2kh+p -> C[(kw*192+kh)*256 + 2c+p]     (S2)
// tmode 3: m=kw*192+kh,n=2c+p  -> C[(c*192+kw)*384 + 2kh+p]     (S5)
// tmode 4: m=c*192+kw, n=2h+q  -> C[(h*128+c)*384 + 2kw+q]      (S6)
// tmode 5: m=h*128+c,  n=w     -> C[(h*360+w)*128 + c], w<360   (S7)
__global__ __launch_bounds__(256) void k_gemm(
    const u16* __restrict__ A1, const u16* __restrict__ A2, int aksplit, int astr, int a2str,
    const u16* __restrict__ B, int bkstr,
    u16* __restrict__ C, int tmode, int cstr,
    const float* __restrict__ bias, const u16* __restrict__ addb,
    int Mvalid, int N, int Kpad, int flags)
{
    __shared__ u16 Tt[128][132];
    int tid = threadIdx.x;
    int l = tid & 63, wv = tid >> 6;
    int wm = wv >> 1, wn = wv & 1;
    int lm = l & 15, kgl = l >> 4;
    int m0 = blockIdx.y*128 + wm*64;
    int n0 = blockIdx.x*128 + wn*64;

    int ab1[4], ab2[4];
    #pragma unroll
    for(int i2=0;i2<4;i2++){
        int mi = m0 + i2*16 + lm;
        ab1[i2] = mi*astr;
        ab2[i2] = mi*a2str;
    }
    int bn[4];
    #pragma unroll
    for(int j2=0;j2<4;j2++) bn[j2] = (n0 + j2*16 + lm)*8;

    f32x4 acc[4][4];
    #pragma unroll
    for(int i2=0;i2<4;i2++)
        #pragma unroll
        for(int j2=0;j2<4;j2++)
            acc[i2][j2] = (f32x4){0.0f,0.0f,0.0f,0.0f};

    for(int k0=0; k0<Kpad; k0+=32){
        int kk = k0 + kgl*8;
        bool s1v = kk < aksplit;
        const u16* Ab = s1v ? A1 : A2;
        int kof = s1v ? kk : kk - aksplit;
        bf16x8 af[4];
        #pragma unroll
        for(int i2=0;i2<4;i2++)
            af[i2] = *(const bf16x8*)(Ab + (s1v ? ab1[i2] : ab2[i2]) + kof);
        const u16* Bb = B + (size_t)((k0>>3) + kgl)*bkstr;
        bf16x8 bf[4];
        #pragma unroll
        for(int j2=0;j2<4;j2++)
            bf[j2] = *(const bf16x8*)(Bb + bn[j2]);
        #pragma unroll
        for(int i2=0;i2<4;i2++)
            #pragma unroll
            for(int j2=0;j2<4;j2++)
                acc[i2][j2] = __builtin_amdgcn_mfma_f32_16x16x32_bf16(af[i2], bf[j2], acc[i2][j2], 0,0,0);
    }

    if(tmode == 0){
        #pragma unroll
        for(int i2=0;i2<4;i2++){
            #pragma unroll
            for(int r=0;r<4;r++){
                int m = m0 + i2*16 + kgl*4 + r;
                if(m >= Mvalid) continue;
                long mb = (long)m*cstr;
                #pragma unroll
                for(int j2=0;j2<4;j2++){
                    int n = n0 + j2*16 + lm;
                    if(n >= N) continue;
                    float v = acc[i2][j2][r];
                    if(bias) v += bias[n];
                    if(flags & 1) v = gelu_f(v);
                    if((flags & 2) && !(n & 1)) v = fmaxf(v, 0.0f);
                    long ca = mb + n;
                    if(addb) v += bf2f(addb[ca]);
                    C[ca] = f2bf(v);
                }
            }
        }
        return;
    }
    // stage tile to LDS
    #pragma unroll
    for(int i2=0;i2<4;i2++)
        #pragma unroll
        for(int j2=0;j2<4;j2++)
            #pragma unroll
            for(int r=0;r<4;r++)
                Tt[wm*64+i2*16+kgl*4+r][wn*64+j2*16+lm] = f2bf(acc[i2][j2][r]);
    __syncthreads();
    int m0b = blockIdx.y*128, n0b = blockIdx.x*128;
    if(tmode <= 4){
        #pragma unroll
        for(int it=0; it<8; it++){
            int g = tid + it*256;
            int gn = g & 63, gm = g >> 6;
            int ml = gm*4, nl = gn*2;
            int mg = m0b + ml, ng = n0b + nl;
            long base;
            if(tmode == 1){
                int c = mg>>8, h = mg&255, kw = ng>>1;
                base = ((long)(kw*128 + c))*512 + 2*h;
            } else if(tmode == 2){
                int kw = mg>>7, c = mg&127, kh = ng>>1;
                base = ((long)(kw*192 + kh))*256 + 2*c;
            } else if(tmode == 3){
                int kw = (int)(((unsigned)mg*43691u)>>23);
                int kh = mg - kw*192;
                int c = ng>>1;
                base = ((long)(c*192 + kw))*384 + 2*kh;
            } else {
                int c = (int)(((unsigned)mg*43691u)>>23);
                int kw = mg - c*192;
                int h = ng>>1;
                base = ((long)(h*128 + c))*384 + 2*kw;
            }
            us8 v;
            #pragma unroll
            for(int i=0;i<4;i++){
                v[2*i]   = Tt[ml+i][nl];
                v[2*i+1] = Tt[ml+i][nl+1];
            }
            *(us8*)(C + base) = v;
        }
    } else {
        #pragma unroll
        for(int it=0; it<8; it++){
            int g = tid + it*256;
            int nl = g & 127, gm = g >> 7;
            int ml = gm*8;
            int mg = m0b + ml, ng = n0b + nl;
            if(ng < 360){
                int h = mg >> 7;
                long base = ((long)(h*360 + ng))*128 + (mg & 127);
                us8 v;
                #pragma unroll
                for(int j=0;j<8;j++) v[j] = Tt[ml+j][nl];
                *(us8*)(C + base) = v;
            }
        }
    }
}

// ============ launch ============
extern "C" void kernel_launch(void* const* d_in, const int* in_sizes, int n_in,
                              void* d_out, int out_size, void* d_ws, size_t ws_size,
                              hipStream_t stream) {
    const float* x       = (const float*)d_in[0];
    const float* enc_w0  = (const float*)d_in[1];
    const float* enc_b0  = (const float*)d_in[2];
    const float* enc_w1  = (const float*)d_in[3];
    const float* pos     = (const float*)d_in[4];
    const float* n0w     = (const float*)d_in[5];
    const float* n0b     = (const float*)d_in[6];
    const float* w0      = (const float*)d_in[7];
    const float* w1      = (const float*)d_in[8];
    const float* wout    = (const float*)d_in[9];
    const float* isw     = (const float*)d_in[10];
    const float* isb     = (const float*)d_in[11];
    const float* n1w     = (const float*)d_in[12];
    const float* n1b     = (const float*)d_in[13];
    const float* fc1w    = (const float*)d_in[14];
    const float* fc1b    = (const float*)d_in[15];
    const float* fc2w    = (const float*)d_in[16];
    const float* fc2b    = (const float*)d_in[17];
    const float* dec_w0  = (const float*)d_in[18];
    const float* dec_b0  = (const float*)d_in[19];
    const float* dec_w1  = (const float*)d_in[20];
    float* out = (float*)d_out;

    u16* ws = (u16*)d_ws;
    size_t off = 0;
    auto al = [&](size_t n){ u16* p = ws + off; off += (n + 63) & ~(size_t)63; return p; };
    u16* TWF  = al(147456);
    u16* THF  = al(196608);
    u16* THI  = al(196608);
    u16* TWI  = al(147456);
    u16* W0P  = al(524288);
    u16* W1P  = al(1048576);
    u16* WOP  = al(524288);
    u16* ISWP = al(65536);
    u16* FC1P = al(131072);
    u16* FC2P = al(131072);
    u16* EW1P = al(16384);
    u16* DW0P = al(20480);
    u16* POSP = al((size_t)NPAD*128);
    u16* XT2  = al((size_t)NPAD*32);
    u16* CURP = al((size_t)NPAD*128);
    u16* XNP  = al((size_t)NPAD*128);
    u16* YP   = al((size_t)NPAD*128);
    u16* XNC  = al((size_t)32768*384);   // [c*256+h][384]
    u16* A2b  = al((size_t)24576*512);   // [kw*128+c][2h+q]   (also A5: [h*128+c][2kw+q])
    u16* A3b  = al((size_t)36864*256);   // [kw*192+kh][2c+p]  (also A4: [c*192+kw][2kh+p])
    u16* H1   = al((size_t)36864*512);   // also BIG [pt][256]
    u16* H2   = al((size_t)36864*512);   // also ENC [pt][128]
    u16* IST  = al(4096);                // 2048 f32 stats
    float* ISTAT = (float*)IST;
    u16* A4b = A3b;
    u16* A5b = A2b;
    u16* BIG = H1;
    u16* ENC = H2;

    dim3 blk(256);
    // zero pads/stats (every launch: deterministic, replay-safe)
    k_zero<<<dim3(6144), blk, 0, stream>>>(XNC, (long)32768*384);
    k_zero<<<dim3(2),    blk, 0, stream>>>(IST, 4096);

    // packs
    k_pack_twf<<<dim3((147456+255)/256), blk, 0, stream>>>(TWF);
    k_pack_thf<<<dim3((196608+255)/256), blk, 0, stream>>>(THF);
    k_pack_thi<<<dim3((196608+255)/256), blk, 0, stream>>>(THI);
    k_pack_twi<<<dim3((147456+255)/256), blk, 0, stream>>>(TWI);
    k_pack_cw<<<dim3((131072+255)/256,1,4), blk, 0, stream>>>(w0,   W0P, 128, 256, 2*128*256, 131072);
    k_pack_cw<<<dim3((262144+255)/256,1,4), blk, 0, stream>>>(w1,   W1P, 256, 256, 2*256*256, 262144);
    k_pack_cw<<<dim3((131072+255)/256,1,4), blk, 0, stream>>>(wout, WOP, 256, 128, 2*256*128, 131072);
    k_pack_rw<<<dim3((16384+255)/256,1,4),  blk, 0, stream>>>(isw,  ISWP, 128, 128, 16, 128*128, 16384);
    k_pack_rw<<<dim3((32768+255)/256,1,4),  blk, 0, stream>>>(fc1w, FC1P, 256, 128, 16, 256*128, 32768);
    k_pack_rw<<<dim3((32768+255)/256,1,4),  blk, 0, stream>>>(fc2w, FC2P, 128, 256, 32, 128*256, 32768);
    k_pack_rw<<<dim3((16384+255)/256,1,1),  blk, 0, stream>>>(enc_w1, EW1P, 128, 128, 16, 0, 0);
    k_pack_rw<<<dim3((20480+255)/256,1,1),  blk, 0, stream>>>(dec_w0, DW0P, 128, 130, 20, 0, 0);
    k_post<<<dim3(1019), blk, 0, stream>>>(pos, POSP);
    k_xt2 <<<dim3((NP+255)/256), blk, 0, stream>>>(x, XT2);

    const u16* nu = nullptr;
    const float* nf = nullptr;
    const int BIGV = 1<<28;
    auto G = [&](const u16* A1v, const u16* A2v, int aksplit, int astr, int a2str,
                 const u16* Bv, int bkstr, u16* Cv, int tmode, int cstr,
                 const float* bias, const u16* addb,
                 int Mgrid, int Mvalid, int N, int Kpad, int flags){
        dim3 g((N+127)/128, (Mgrid+127)/128, 1);
        k_gemm<<<g, blk, 0, stream>>>(A1v, A2v, aksplit, astr, a2str, Bv, bkstr,
            Cv, tmode, cstr, bias, addb, Mvalid, N, Kpad, flags);
    };

    // encoder
    k_enc0<<<dim3((NP*16+255)/256), blk, 0, stream>>>(x, enc_w0, enc_b0, ENC);
    G(ENC, ENC, BIGV, 128, 128, EW1P, 1024, CURP, 0, 128, nf, POSP, NPAD, NP, 128, 128, 0);

    for(int l=0; l<4; l++){
        float* st0 = ISTAT + (2*l)*256;
        float* st1 = ISTAT + (2*l+1)*256;
        k_istat<<<dim3(128), blk, 0, stream>>>(CURP, st0);
        k_apply_t<<<dim3(1019), blk, 0, stream>>>(CURP, XNP, XNC, st0, n0w+l*128, n0b+l*128);
        // S1 rdft: XNC x TWF -> A2 (mode1)
        G(XNC, XNC, BIGV, 384, 384, TWF, 3072, A2b, 1, 0, nf, nu, 32768, 32768, 384, 384, 0);
        // S2 H-DFT fwd: A2 x THF -> A3 (mode2)
        G(A2b, A2b, BIGV, 512, 512, THF, 3072, A3b, 2, 0, nf, nu, 24576, 24576, 384, 512, 0);
        // S3 cmix w0 (CReLU even n): A3 x W0P -> H1 [pt][512]
        G(A3b, A3b, BIGV, 256, 256, W0P + (size_t)l*131072, 4096, H1, 0, 512, nf, nu, 36864, 36864, 512, 256, 2);
        // S4 cmix w1: H1 x W1P -> H2
        G(H1, H1, BIGV, 512, 512, W1P + (size_t)l*262144, 4096, H2, 0, 512, nf, nu, 36864, 36864, 512, 512, 2);
        // S5 cmix wout: H2 x WOP -> A4 (mode3)
        G(H2, H2, BIGV, 512, 512, WOP + (size_t)l*131072, 2048, A4b, 3, 0, nf, nu, 36864, 36864, 256, 512, 0);
        // S6 H-DFT inv: A4 x THI -> A5 (mode4)
        G(A4b, A4b, BIGV, 384, 384, THI, 4096, A5b, 4, 0, nf, nu, 24576, 24576, 512, 384, 0);
        // S7 irdft: A5 x TWI -> YP [pt][128] (mode5)
        G(A5b, A5b, BIGV, 384, 384, TWI, 3072, YP, 5, 0, nf, nu, 23168, 23168, 384, 384, 0);
        // inner skip: CUR = isw*XN + isb + Y
        G(XNP, XNP, BIGV, 128, 128, ISWP + (size_t)l*16384, 1024, CURP, 0, 128, isb+l*128, YP, NPAD, NP, 128, 128, 0);
        // norm1
        k_istat<<<dim3(128), blk, 0, stream>>>(CURP, st1);
        k_apply<<<dim3((NP*16+255)/256), blk, 0, stream>>>(CURP, YP, st1, n1w+l*128, n1b+l*128);
        // fc1 + gelu -> BIG [pt][256]
        G(YP, YP, BIGV, 128, 128, FC1P + (size_t)l*32768, 2048, BIG, 0, 256, fc1b+l*256, nu, NPAD, NP, 256, 128, 1);
        // fc2 + outer skip(XN) -> CUR
        G(BIG, BIG, BIGV, 256, 256, FC2P + (size_t)l*32768, 1024, CURP, 0, 128, fc2b+l*128, XNP, NPAD, NP, 128, 256, 0);
    }
    // decoder conv0 (concat CUR, x) + gelu -> XNP
    G(CURP, XT2, 128, 128, 32, DW0P, 1024, XNP, 0, 128, dec_b0, nu, NPAD, NP, 128, 160, 1);
    k_dec1<<<dim3((NP+255)/256), blk, 0, stream>>>(XNP, dec_w1, out);
}

// Round 6
// 1877.760 us; speedup vs baseline: 3.6673x; 1.1264x over previous
//
#include <hip/hip_runtime.h>
#include <math.h>

#define NP 65160        // 181*360
#define NPAD 65280

typedef unsigned short u16;
typedef __attribute__((ext_vector_type(8))) short bf16x8;
typedef __attribute__((ext_vector_type(8))) unsigned short us8;
typedef __attribute__((ext_vector_type(4))) float f32x4;

__device__ __forceinline__ u16 f2bf(float f){
    unsigned u = __builtin_bit_cast(unsigned, f);
    return (u16)((u + 0x7FFFu + ((u>>16)&1u)) >> 16);
}
__device__ __forceinline__ float bf2f(u16 h){
    unsigned u = ((unsigned)h)<<16;
    return __builtin_bit_cast(float, u);
}
__device__ __forceinline__ float gelu_f(float x){
    return 0.5f*x*(1.0f+erff(x*0.70710678118654752f));
}

__global__ void k_zero(u16* __restrict__ p, long n){
    long i = ((long)blockIdx.x*256 + threadIdx.x)*8;
    if(i+8 <= n){ us8 z = {0,0,0,0,0,0,0,0}; *(us8*)(p+i) = z; }
}

// ============ B packs: dst[kg][n][8], k = kg*8+e, zero padded ============
__global__ void k_pack_twf(u16* __restrict__ dst){   // [48][384][8]: k=w, n=2kw+q
    int i = blockIdx.x*256+threadIdx.x; if(i >= 48*384*8) return;
    int e = i&7, n = (i>>3)%384, kg = i/(384*8);
    int k = kg*8+e, kw = n>>1, q = n&1;
    float v = 0.0f;
    if(k < 360 && kw < 181){
        float inv = 1.0f/sqrtf(65160.0f);
        float th = 6.28318530717958647692f*(float)((k*kw)%360)/360.0f;
        v = q ? -sinf(th)*inv : cosf(th)*inv;
    }
    dst[i] = f2bf(v);
}
__global__ void k_pack_thf(u16* __restrict__ dst){   // [64][384][8]: k=2h+q, n=2kh+p
    int i = blockIdx.x*256+threadIdx.x; if(i >= 64*384*8) return;
    int e = i&7, n = (i>>3)%384, kg = i/(384*8);
    int k = kg*8+e;
    float v = 0.0f;
    if(k < 362 && n < 362){
        int h = k>>1, q = k&1, kh = n>>1, p = n&1;
        float th = 6.28318530717958647692f*(float)((h*kh)%181)/181.0f;
        float c = cosf(th), s = sinf(th);
        v = (q==0) ? (p==0? c : -s) : (p==0? s : c);
    }
    dst[i] = f2bf(v);
}
__global__ void k_pack_thi(u16* __restrict__ dst){   // [48][512][8]: k=2kh+p, n=2h+q
    int i = blockIdx.x*256+threadIdx.x; if(i >= 48*512*8) return;
    int e = i&7, n = (i>>3)%512, kg = i/(512*8);
    int k = kg*8+e;
    float v = 0.0f;
    if(k < 362 && n < 362){
        int kh = k>>1, p = k&1, h = n>>1, q = n&1;
        float th = 6.28318530717958647692f*(float)((kh*h)%181)/181.0f;
        float c = cosf(th), s = sinf(th);
        v = (q==0) ? (p==0? c : -s) : (p==0? s : c);
    }
    dst[i] = f2bf(v);
}
__global__ void k_pack_twi(u16* __restrict__ dst){   // [48][384][8]: k=2kw+q, n=w
    int i = blockIdx.x*256+threadIdx.x; if(i >= 48*384*8) return;
    int e = i&7, n = (i>>3)%384, kg = i/(384*8);
    int k = kg*8+e, kw = k>>1, q = k&1;
    float v = 0.0f;
    if(k < 362 && n < 360){
        float inv = 1.0f/sqrtf(65160.0f);
        float eps = (kw==0 || kw==180) ? 1.0f : 2.0f;
        float th = 6.28318530717958647692f*(float)((n*kw)%360)/360.0f;
        v = q ? -eps*sinf(th)*inv : eps*cosf(th)*inv;
    }
    dst[i] = f2bf(v);
}
__global__ void k_pack_cw(const float* __restrict__ src, u16* __restrict__ dst,
                          int CIN, int COUT, int lss, int lsd){
    int z = blockIdx.z;
    int Npad = 2*COUT, KG = (2*CIN)/8;
    int tot = KG*Npad*8;
    int i = blockIdx.x*256+threadIdx.x; if(i >= tot) return;
    int e = i&7, n = (i>>3)%Npad, kg = i/(Npad*8);
    int k = kg*8+e, ci = k>>1, q = k&1, co = n>>1, p = n&1;
    float re = src[(size_t)z*lss + ci*COUT + co];
    float im = src[(size_t)z*lss + CIN*COUT + ci*COUT + co];
    float v = (p==0) ? (q==0? re : -im) : (q==0? im : re);
    dst[(size_t)z*lsd + i] = f2bf(v);
}
__global__ void k_pack_rw(const float* __restrict__ src, u16* __restrict__ dst,
                          int Nn, int Ks, int KG, int lss, int lsd){
    int z = blockIdx.z;
    int tot = KG*Nn*8;
    int i = blockIdx.x*256+threadIdx.x; if(i >= tot) return;
    int e = i&7, n = (i>>3)%Nn, kg = i/(Nn*8);
    int k = kg*8+e;
    float v = (k < Ks) ? src[(size_t)z*lss + n*Ks + k] : 0.0f;
    dst[(size_t)z*lsd + i] = f2bf(v);
}

// ============ pointwise ============
__global__ void k_enc0(const float* __restrict__ x, const float* __restrict__ w,
                       const float* __restrict__ b, u16* __restrict__ out){
    int i = blockIdx.x*256+threadIdx.x;
    if(i >= NP*16) return;
    int p = i>>4, c8 = (i&15)*8;
    float x0 = x[p], x1 = x[NP+p];
    us8 o;
    #pragma unroll
    for(int j=0;j<8;j++){
        int e = c8+j;
        float v = w[e*2]*x0 + w[e*2+1]*x1 + b[e];
        o[j] = f2bf(gelu_f(v));
    }
    *(us8*)(out + (size_t)p*128 + c8) = o;
}
__global__ void k_xt2(const float* __restrict__ x, u16* __restrict__ dst){
    int p = blockIdx.x*256+threadIdx.x; if(p >= NP) return;
    us8 z = {0,0,0,0,0,0,0,0};
    z[0] = f2bf(x[p]); z[1] = f2bf(x[NP+p]);
    *(us8*)(dst + (size_t)p*32) = z;
    us8 z2 = {0,0,0,0,0,0,0,0};
    *(us8*)(dst + (size_t)p*32 + 8)  = z2;
    *(us8*)(dst + (size_t)p*32 + 16) = z2;
    *(us8*)(dst + (size_t)p*32 + 24) = z2;
}
__global__ void k_dec1(const u16* __restrict__ hid, const float* __restrict__ w,
                       float* __restrict__ out){
    int p = blockIdx.x*256+threadIdx.x; if(p >= NP) return;
    float a0=0.0f, a1=0.0f;
    #pragma unroll 4
    for(int k8=0;k8<16;k8++){
        us8 v = *(const us8*)(hid + (size_t)p*128 + k8*8);
        #pragma unroll
        for(int j=0;j<8;j++){
            float f = bf2f(v[j]);
            a0 = fmaf(w[k8*8+j], f, a0);
            a1 = fmaf(w[128+k8*8+j], f, a1);
        }
    }
    out[p] = a0; out[NP+p] = a1;
}

// ============ instance norm ============
__global__ __launch_bounds__(256) void k_istat(const u16* __restrict__ X, float* __restrict__ stat){
    int t = threadIdx.x;
    int c8 = (t&15)*8;
    float s[8], s2[8];
    #pragma unroll
    for(int j=0;j<8;j++){ s[j]=0.0f; s2[j]=0.0f; }
    for(int p = blockIdx.x*16 + (t>>4); p < NP; p += gridDim.x*16){
        us8 v = *(const us8*)(X + (size_t)p*128 + c8);
        #pragma unroll
        for(int j=0;j<8;j++){ float f = bf2f(v[j]); s[j]+=f; s2[j]=fmaf(f,f,s2[j]); }
    }
    __shared__ float L[256][8];
    #pragma unroll
    for(int j=0;j<8;j++) L[t][j]=s[j];
    __syncthreads();
    for(int st=128; st>=16; st>>=1){
        if(t<st){
            #pragma unroll
            for(int j=0;j<8;j++) L[t][j]+=L[t+st][j];
        }
        __syncthreads();
    }
    if(t<16){
        #pragma unroll
        for(int j=0;j<8;j++) atomicAdd(&stat[t*8+j], L[t][j]);
    }
    __syncthreads();
    #pragma unroll
    for(int j=0;j<8;j++) L[t][j]=s2[j];
    __syncthreads();
    for(int st=128; st>=16; st>>=1){
        if(t<st){
            #pragma unroll
            for(int j=0;j<8;j++) L[t][j]+=L[t+st][j];
        }
        __syncthreads();
    }
    if(t<16){
        #pragma unroll
        for(int j=0;j<8;j++) atomicAdd(&stat[128+t*8+j], L[t][j]);
    }
}
__global__ __launch_bounds__(256) void k_apply_t(
    const u16* __restrict__ X, u16* __restrict__ outp, u16* __restrict__ outc,
    const float* __restrict__ stat, const float* __restrict__ gw, const float* __restrict__ gb)
{
    __shared__ u16 T[128][72];
    __shared__ float SA_[128], SB_[128];
    int t = threadIdx.x;
    if(t < 128){
        float mu = stat[t]*(1.0f/(float)NP);
        float var = stat[128+t]*(1.0f/(float)NP) - mu*mu;
        var = fmaxf(var, 0.0f);
        float rstd = 1.0f/sqrtf(var + 1e-6f);
        float a = rstd*gw[t];
        SA_[t] = a; SB_[t] = gb[t] - mu*a;
    }
    __syncthreads();
    int p0 = blockIdx.x*64;
    int pl = t>>2, cc = (t&3)*32;
    int p = p0 + pl;
    if(p < NP){
        #pragma unroll
        for(int jj=0;jj<4;jj++){
            us8 v = *(const us8*)(X + (size_t)p*128 + cc + jj*8);
            us8 o;
            #pragma unroll
            for(int j=0;j<8;j++){
                int c = cc + jj*8 + j;
                o[j] = f2bf(fmaf(bf2f(v[j]), SA_[c], SB_[c]));
            }
            *(us8*)(outp + (size_t)p*128 + cc + jj*8) = o;
            #pragma unroll
            for(int j=0;j<8;j++) T[cc+jj*8+j][pl] = o[j];
        }
    }
    __syncthreads();
    int c = t>>1, half = t&1;
    int pbase = p0 + half*32;
    #pragma unroll
    for(int jj=0;jj<4;jj++){
        int pp = pbase + jj*8;
        if(pp + 8 <= NP){
            int hh = pp/360, ww = pp - hh*360;
            *(us8*)(outc + ((size_t)c*256 + hh)*384 + ww) = *(const us8*)(&T[c][half*32 + jj*8]);
        }
    }
}
__global__ __launch_bounds__(256) void k_apply(
    const u16* __restrict__ X, u16* __restrict__ outp,
    const float* __restrict__ stat, const float* __restrict__ gw, const float* __restrict__ gb)
{
    __shared__ float SA_[128], SB_[128];
    int t = threadIdx.x;
    if(t < 128){
        float mu = stat[t]*(1.0f/(float)NP);
        float var = stat[128+t]*(1.0f/(float)NP) - mu*mu;
        var = fmaxf(var, 0.0f);
        float rstd = 1.0f/sqrtf(var + 1e-6f);
        float a = rstd*gw[t];
        SA_[t] = a; SB_[t] = gb[t] - mu*a;
    }
    __syncthreads();
    int i = blockIdx.x*256 + t;
    if(i >= NP*16) return;
    int p = i>>4, c8 = (i&15)*8;
    us8 v = *(const us8*)(X + (size_t)p*128 + c8);
    us8 o;
    #pragma unroll
    for(int j=0;j<8;j++) o[j] = f2bf(fmaf(bf2f(v[j]), SA_[c8+j], SB_[c8+j]));
    *(us8*)(outp + (size_t)p*128 + c8) = o;
}
__global__ __launch_bounds__(256) void k_post(const float* __restrict__ src, u16* __restrict__ dst){
    __shared__ u16 T[128][72];
    int t = threadIdx.x;
    int p0 = blockIdx.x*64;
    int c = t>>1, half = t&1;
    int pbase = p0 + half*32;
    #pragma unroll
    for(int jj=0;jj<4;jj++){
        int pp = pbase + jj*8;
        us8 v = {0,0,0,0,0,0,0,0};
        if(pp + 8 <= NP){
            #pragma unroll
            for(int j=0;j<8;j++) v[j] = f2bf(src[(size_t)c*NP + pp + j]);
        }
        *(us8*)(&T[c][half*32 + jj*8]) = v;
    }
    __syncthreads();
    int pl = t>>2, cc = (t&3)*32;
    int p = p0 + pl;
    if(p < NP){
        #pragma unroll
        for(int jj=0;jj<4;jj++){
            us8 o;
            #pragma unroll
            for(int j=0;j<8;j++) o[j] = T[cc+jj*8+j][pl];
            *(us8*)(dst + (size_t)p*128 + cc + jj*8) = o;
        }
    }
}

// ============ fused spectral channel-MLP: S3+S4+S5 ============
// per block: 64 spectral points (m = kw*192+kh), H1/H2 in LDS.
// A3 [36864][256]; out A4[(c*192+kw)*384 + 2kh+p]
__global__ __launch_bounds__(512) void k_smlp(
    const u16* __restrict__ A3, const u16* __restrict__ W0,
    const u16* __restrict__ W1, const u16* __restrict__ WO,
    u16* __restrict__ A4)
{
    __shared__ u16 Hs0[64][520];
    __shared__ u16 Hs1[64][520];
    int tid = threadIdx.x;
    int l = tid & 63, wv = tid >> 6;
    int wm = wv >> 2, wn = wv & 3;
    int lm = l & 15, kg = l >> 4;
    int m0 = blockIdx.x * 64;
    int mw = wm * 32;

    // ---- stage 1: H1[64][512] = A3tile x W0 (K=256), CReLU even n ----
    f32x4 acc[2][8];
    #pragma unroll
    for(int i2=0;i2<2;i2++)
        #pragma unroll
        for(int j2=0;j2<8;j2++) acc[i2][j2] = (f32x4){0.f,0.f,0.f,0.f};
    {
        const u16* a0p = A3 + (size_t)(m0 + mw + lm)*256 + kg*8;
        const u16* a1p = A3 + (size_t)(m0 + mw + 16 + lm)*256 + kg*8;
        for(int k0=0;k0<256;k0+=32){
            bf16x8 af0 = *(const bf16x8*)(a0p + k0);
            bf16x8 af1 = *(const bf16x8*)(a1p + k0);
            const u16* Bb = W0 + (size_t)((k0>>3)+kg)*4096 + (wn*128+lm)*8;
            bf16x8 bf[8];
            #pragma unroll
            for(int j2=0;j2<8;j2++) bf[j2] = *(const bf16x8*)(Bb + j2*128);
            #pragma unroll
            for(int j2=0;j2<8;j2++){
                acc[0][j2] = __builtin_amdgcn_mfma_f32_16x16x32_bf16(af0, bf[j2], acc[0][j2], 0,0,0);
                acc[1][j2] = __builtin_amdgcn_mfma_f32_16x16x32_bf16(af1, bf[j2], acc[1][j2], 0,0,0);
            }
        }
        #pragma unroll
        for(int i2=0;i2<2;i2++)
            #pragma unroll
            for(int j2=0;j2<8;j2++)
                #pragma unroll
                for(int r=0;r<4;r++){
                    int row = mw + i2*16 + kg*4 + r;
                    int col = wn*128 + j2*16 + lm;
                    float v = acc[i2][j2][r];
                    if(!(col&1)) v = fmaxf(v, 0.0f);
                    Hs0[row][col] = f2bf(v);
                }
    }
    __syncthreads();
    // ---- stage 2: H2 = H1 x W1 (K=512), CReLU even n ----
    #pragma unroll
    for(int i2=0;i2<2;i2++)
        #pragma unroll
        for(int j2=0;j2<8;j2++) acc[i2][j2] = (f32x4){0.f,0.f,0.f,0.f};
    for(int k0=0;k0<512;k0+=32){
        bf16x8 af0 = *(const bf16x8*)(&Hs0[mw + lm][k0 + kg*8]);
        bf16x8 af1 = *(const bf16x8*)(&Hs0[mw + 16 + lm][k0 + kg*8]);
        const u16* Bb = W1 + (size_t)((k0>>3)+kg)*4096 + (wn*128+lm)*8;
        bf16x8 bf[8];
        #pragma unroll
        for(int j2=0;j2<8;j2++) bf[j2] = *(const bf16x8*)(Bb + j2*128);
        #pragma unroll
        for(int j2=0;j2<8;j2++){
            acc[0][j2] = __builtin_amdgcn_mfma_f32_16x16x32_bf16(af0, bf[j2], acc[0][j2], 0,0,0);
            acc[1][j2] = __builtin_amdgcn_mfma_f32_16x16x32_bf16(af1, bf[j2], acc[1][j2], 0,0,0);
        }
    }
    #pragma unroll
    for(int i2=0;i2<2;i2++)
        #pragma unroll
        for(int j2=0;j2<8;j2++)
            #pragma unroll
            for(int r=0;r<4;r++){
                int row = mw + i2*16 + kg*4 + r;
                int col = wn*128 + j2*16 + lm;
                float v = acc[i2][j2][r];
                if(!(col&1)) v = fmaxf(v, 0.0f);
                Hs1[row][col] = f2bf(v);
            }
    __syncthreads();
    // ---- stage 3: O[64][256] = H2 x WO (K=512) ----
    f32x4 acc3[2][4];
    #pragma unroll
    for(int i2=0;i2<2;i2++)
        #pragma unroll
        for(int j2=0;j2<4;j2++) acc3[i2][j2] = (f32x4){0.f,0.f,0.f,0.f};
    for(int k0=0;k0<512;k0+=32){
        bf16x8 af0 = *(const bf16x8*)(&Hs1[mw + lm][k0 + kg*8]);
        bf16x8 af1 = *(const bf16x8*)(&Hs1[mw + 16 + lm][k0 + kg*8]);
        const u16* Bb = WO + (size_t)((k0>>3)+kg)*2048 + (wn*64+lm)*8;
        bf16x8 bf[4];
        #pragma unroll
        for(int j2=0;j2<4;j2++) bf[j2] = *(const bf16x8*)(Bb + j2*128);
        #pragma unroll
        for(int j2=0;j2<4;j2++){
            acc3[0][j2] = __builtin_amdgcn_mfma_f32_16x16x32_bf16(af0, bf[j2], acc3[0][j2], 0,0,0);
            acc3[1][j2] = __builtin_amdgcn_mfma_f32_16x16x32_bf16(af1, bf[j2], acc3[1][j2], 0,0,0);
        }
    }
    __syncthreads();   // all stage-3 LDS reads done before O overwrites Hs0
    #pragma unroll
    for(int i2=0;i2<2;i2++)
        #pragma unroll
        for(int j2=0;j2<4;j2++)
            #pragma unroll
            for(int r=0;r<4;r++)
                Hs0[mw + i2*16 + kg*4 + r][wn*64 + j2*16 + lm] = f2bf(acc3[i2][j2][r]);
    __syncthreads();
    // ---- coalesced store: out row c gets interleave(O[kh][2c],O[kh][2c+1]) ----
    int kw = m0 / 192;
    int kh0 = m0 - kw*192;
    int c = tid >> 2, q = tid & 3;
    long base = ((long)(c*192 + kw))*384 + 2*(kh0 + q*16);
    #pragma unroll
    for(int jj=0;jj<4;jj++){
        us8 v;
        #pragma unroll
        for(int i=0;i<4;i++){
            v[2*i]   = Hs0[q*16 + jj*4 + i][2*c];
            v[2*i+1] = Hs0[q*16 + jj*4 + i][2*c+1];
        }
        *(us8*)(A4 + base + jj*8) = v;
    }
}

// ============ MFMA GEMM, templated on store mode ============
// TMODE 0: C[m*cstr + n] (bias/gelu/relu-even/addb), NO LDS
// TMODE 1: m=c*256+h,  n=2kw+q -> C[(kw*128+c)*512 + 2h+q]
// TMODE 2: m=kw*128+c, n=2kh+p -> C[(kw*192+kh)*256 + 2c+p]
// TMODE 4: m=c*192+kw, n=2h+q  -> C[(h*128+c)*384 + 2kw+q]
// TMODE 5: m=h*128+c,  n=w     -> C[(h*360+w)*128 + c], w<360
template<int TMODE>
__global__ __launch_bounds__(256) void k_gemm(
    const u16* __restrict__ A1, const u16* __restrict__ A2, int aksplit, int astr, int a2str,
    const u16* __restrict__ B, int bkstr,
    u16* __restrict__ C, int cstr,
    const float* __restrict__ bias, const u16* __restrict__ addb,
    int Mvalid, int N, int Kpad, int flags)
{
    int tid = threadIdx.x;
    int l = tid & 63, wv = tid >> 6;
    int wm = wv >> 1, wn = wv & 1;
    int lm = l & 15, kgl = l >> 4;
    int m0 = blockIdx.y*128 + wm*64;
    int n0 = blockIdx.x*128 + wn*64;

    int ab1[4], ab2[4];
    #pragma unroll
    for(int i2=0;i2<4;i2++){
        int mi = m0 + i2*16 + lm;
        ab1[i2] = mi*astr;
        ab2[i2] = mi*a2str;
    }
    int bn[4];
    #pragma unroll
    for(int j2=0;j2<4;j2++) bn[j2] = (n0 + j2*16 + lm)*8;

    f32x4 acc[4][4];
    #pragma unroll
    for(int i2=0;i2<4;i2++)
        #pragma unroll
        for(int j2=0;j2<4;j2++)
            acc[i2][j2] = (f32x4){0.0f,0.0f,0.0f,0.0f};

    for(int k0=0; k0<Kpad; k0+=32){
        int kk = k0 + kgl*8;
        bool s1v = kk < aksplit;
        const u16* Ab = s1v ? A1 : A2;
        int kof = s1v ? kk : kk - aksplit;
        bf16x8 af[4];
        #pragma unroll
        for(int i2=0;i2<4;i2++)
            af[i2] = *(const bf16x8*)(Ab + (s1v ? ab1[i2] : ab2[i2]) + kof);
        const u16* Bb = B + (size_t)((k0>>3) + kgl)*bkstr;
        bf16x8 bf[4];
        #pragma unroll
        for(int j2=0;j2<4;j2++)
            bf[j2] = *(const bf16x8*)(Bb + bn[j2]);
        #pragma unroll
        for(int i2=0;i2<4;i2++)
            #pragma unroll
            for(int j2=0;j2<4;j2++)
                acc[i2][j2] = __builtin_amdgcn_mfma_f32_16x16x32_bf16(af[i2], bf[j2], acc[i2][j2], 0,0,0);
    }

    if constexpr (TMODE == 0){
        #pragma unroll
        for(int i2=0;i2<4;i2++){
            #pragma unroll
            for(int r=0;r<4;r++){
                int m = m0 + i2*16 + kgl*4 + r;
                if(m >= Mvalid) continue;
                long mb = (long)m*cstr;
                #pragma unroll
                for(int j2=0;j2<4;j2++){
                    int n = n0 + j2*16 + lm;
                    if(n >= N) continue;
                    float v = acc[i2][j2][r];
                    if(bias) v += bias[n];
                    if(flags & 1) v = gelu_f(v);
                    if((flags & 2) && !(n & 1)) v = fmaxf(v, 0.0f);
                    long ca = mb + n;
                    if(addb) v += bf2f(addb[ca]);
                    C[ca] = f2bf(v);
                }
            }
        }
    } else {
        __shared__ u16 Tt[128][132];
        #pragma unroll
        for(int i2=0;i2<4;i2++)
            #pragma unroll
            for(int j2=0;j2<4;j2++)
                #pragma unroll
                for(int r=0;r<4;r++)
                    Tt[wm*64+i2*16+kgl*4+r][wn*64+j2*16+lm] = f2bf(acc[i2][j2][r]);
        __syncthreads();
        int m0b = blockIdx.y*128, n0b = blockIdx.x*128;
        if constexpr (TMODE <= 4){
            #pragma unroll
            for(int it=0; it<8; it++){
                int g = tid + it*256;
                int gn = g & 63, gm = g >> 6;
                int ml = gm*4, nl = gn*2;
                int mg = m0b + ml, ng = n0b + nl;
                long base;
                if constexpr (TMODE == 1){
                    int c = mg>>8, h = mg&255, kw = ng>>1;
                    base = ((long)(kw*128 + c))*512 + 2*h;
                } else if constexpr (TMODE == 2){
                    int kw = mg>>7, c = mg&127, kh = ng>>1;
                    base = ((long)(kw*192 + kh))*256 + 2*c;
                } else {
                    int c = (int)(((unsigned)mg*43691u)>>23);
                    int kw = mg - c*192;
                    int h = ng>>1;
                    base = ((long)(h*128 + c))*384 + 2*kw;
                }
                us8 v;
                #pragma unroll
                for(int i=0;i<4;i++){
                    v[2*i]   = Tt[ml+i][nl];
                    v[2*i+1] = Tt[ml+i][nl+1];
                }
                *(us8*)(C + base) = v;
            }
        } else {
            #pragma unroll
            for(int it=0; it<8; it++){
                int g = tid + it*256;
                int nl = g & 127, gm = g >> 7;
                int ml = gm*8;
                int mg = m0b + ml, ng = n0b + nl;
                if(ng < 360){
                    int h = mg >> 7;
                    long base = ((long)(h*360 + ng))*128 + (mg & 127);
                    us8 v;
                    #pragma unroll
                    for(int j=0;j<8;j++) v[j] = Tt[ml+j][nl];
                    *(us8*)(C + base) = v;
                }
            }
        }
    }
}

// ============ launch ============
extern "C" void kernel_launch(void* const* d_in, const int* in_sizes, int n_in,
                              void* d_out, int out_size, void* d_ws, size_t ws_size,
                              hipStream_t stream) {
    const float* x       = (const float*)d_in[0];
    const float* enc_w0  = (const float*)d_in[1];
    const float* enc_b0  = (const float*)d_in[2];
    const float* enc_w1  = (const float*)d_in[3];
    const float* pos     = (const float*)d_in[4];
    const float* n0w     = (const float*)d_in[5];
    const float* n0b     = (const float*)d_in[6];
    const float* w0      = (const float*)d_in[7];
    const float* w1      = (const float*)d_in[8];
    const float* wout    = (const float*)d_in[9];
    const float* isw     = (const float*)d_in[10];
    const float* isb     = (const float*)d_in[11];
    const float* n1w     = (const float*)d_in[12];
    const float* n1b     = (const float*)d_in[13];
    const float* fc1w    = (const float*)d_in[14];
    const float* fc1b    = (const float*)d_in[15];
    const float* fc2w    = (const float*)d_in[16];
    const float* fc2b    = (const float*)d_in[17];
    const float* dec_w0  = (const float*)d_in[18];
    const float* dec_b0  = (const float*)d_in[19];
    const float* dec_w1  = (const float*)d_in[20];
    float* out = (float*)d_out;

    u16* ws = (u16*)d_ws;
    size_t off = 0;
    auto al = [&](size_t n){ u16* p = ws + off; off += (n + 63) & ~(size_t)63; return p; };
    u16* TWF  = al(147456);
    u16* THF  = al(196608);
    u16* THI  = al(196608);
    u16* TWI  = al(147456);
    u16* W0P  = al(524288);
    u16* W1P  = al(1048576);
    u16* WOP  = al(524288);
    u16* ISWP = al(65536);
    u16* FC1P = al(131072);
    u16* FC2P = al(131072);
    u16* EW1P = al(16384);
    u16* DW0P = al(20480);
    u16* POSP = al((size_t)NPAD*128);
    u16* XT2  = al((size_t)NPAD*32);
    u16* CURP = al((size_t)NPAD*128);
    u16* XNP  = al((size_t)NPAD*128);
    u16* YP   = al((size_t)NPAD*128);
    u16* XNC  = al((size_t)32768*384);   // [c*256+h][384]
    u16* A2b  = al((size_t)24576*512);   // [kw*128+c][2h+q]  (also A5: [h*128+c][2kw+q])
    u16* A3b  = al((size_t)36864*256);   // [kw*192+kh][2c+p]
    u16* A4b  = al((size_t)24576*384);   // [c*192+kw][2kh+p]
    u16* BIG  = al((size_t)NPAD*256);    // fc1 out [pt][256]; also ENC [pt][128]
    u16* IST  = al(4096);
    float* ISTAT = (float*)IST;
    u16* A5b = A2b;
    u16* ENC = BIG;

    dim3 blk(256);
    k_zero<<<dim3(6144), blk, 0, stream>>>(XNC, (long)32768*384);
    k_zero<<<dim3(2),    blk, 0, stream>>>(IST, 4096);

    // packs
    k_pack_twf<<<dim3((147456+255)/256), blk, 0, stream>>>(TWF);
    k_pack_thf<<<dim3((196608+255)/256), blk, 0, stream>>>(THF);
    k_pack_thi<<<dim3((196608+255)/256), blk, 0, stream>>>(THI);
    k_pack_twi<<<dim3((147456+255)/256), blk, 0, stream>>>(TWI);
    k_pack_cw<<<dim3((131072+255)/256,1,4), blk, 0, stream>>>(w0,   W0P, 128, 256, 2*128*256, 131072);
    k_pack_cw<<<dim3((262144+255)/256,1,4), blk, 0, stream>>>(w1,   W1P, 256, 256, 2*256*256, 262144);
    k_pack_cw<<<dim3((131072+255)/256,1,4), blk, 0, stream>>>(wout, WOP, 256, 128, 2*256*128, 131072);
    k_pack_rw<<<dim3((16384+255)/256,1,4),  blk, 0, stream>>>(isw,  ISWP, 128, 128, 16, 128*128, 16384);
    k_pack_rw<<<dim3((32768+255)/256,1,4),  blk, 0, stream>>>(fc1w, FC1P, 256, 128, 16, 256*128, 32768);
    k_pack_rw<<<dim3((32768+255)/256,1,4),  blk, 0, stream>>>(fc2w, FC2P, 128, 256, 32, 128*256, 32768);
    k_pack_rw<<<dim3((16384+255)/256,1,1),  blk, 0, stream>>>(enc_w1, EW1P, 128, 128, 16, 0, 0);
    k_pack_rw<<<dim3((20480+255)/256,1,1),  blk, 0, stream>>>(dec_w0, DW0P, 128, 130, 20, 0, 0);
    k_post<<<dim3(1019), blk, 0, stream>>>(pos, POSP);
    k_xt2 <<<dim3((NP+255)/256), blk, 0, stream>>>(x, XT2);

    const u16* nu = nullptr;
    const float* nf = nullptr;
    const int BIGV = 1<<28;
    auto G = [&](int tmode, const u16* A1v, const u16* A2v, int aksplit, int astr, int a2str,
                 const u16* Bv, int bkstr, u16* Cv, int cstr,
                 const float* bias, const u16* addb,
                 int Mgrid, int Mvalid, int N, int Kpad, int flags){
        dim3 g((N+127)/128, (Mgrid+127)/128, 1);
        switch(tmode){
        case 0: k_gemm<0><<<g, blk, 0, stream>>>(A1v,A2v,aksplit,astr,a2str,Bv,bkstr,Cv,cstr,bias,addb,Mvalid,N,Kpad,flags); break;
        case 1: k_gemm<1><<<g, blk, 0, stream>>>(A1v,A2v,aksplit,astr,a2str,Bv,bkstr,Cv,cstr,bias,addb,Mvalid,N,Kpad,flags); break;
        case 2: k_gemm<2><<<g, blk, 0, stream>>>(A1v,A2v,aksplit,astr,a2str,Bv,bkstr,Cv,cstr,bias,addb,Mvalid,N,Kpad,flags); break;
        case 4: k_gemm<4><<<g, blk, 0, stream>>>(A1v,A2v,aksplit,astr,a2str,Bv,bkstr,Cv,cstr,bias,addb,Mvalid,N,Kpad,flags); break;
        case 5: k_gemm<5><<<g, blk, 0, stream>>>(A1v,A2v,aksplit,astr,a2str,Bv,bkstr,Cv,cstr,bias,addb,Mvalid,N,Kpad,flags); break;
        }
    };

    // encoder
    k_enc0<<<dim3((NP*16+255)/256), blk, 0, stream>>>(x, enc_w0, enc_b0, ENC);
    G(0, ENC, ENC, BIGV, 128, 128, EW1P, 1024, CURP, 128, nf, POSP, NPAD, NP, 128, 128, 0);

    for(int l=0; l<4; l++){
        float* st0 = ISTAT + (2*l)*256;
        float* st1 = ISTAT + (2*l+1)*256;
        k_istat<<<dim3(128), blk, 0, stream>>>(CURP, st0);
        k_apply_t<<<dim3(1019), blk, 0, stream>>>(CURP, XNP, XNC, st0, n0w+l*128, n0b+l*128);
        // S1 rdft: XNC x TWF -> A2
        G(1, XNC, XNC, BIGV, 384, 384, TWF, 3072, A2b, 0, nf, nu, 32768, 32768, 384, 384, 0);
        // S2 H-DFT fwd: A2 x THF -> A3
        G(2, A2b, A2b, BIGV, 512, 512, THF, 3072, A3b, 0, nf, nu, 24576, 24576, 384, 512, 0);
        // fused spectral channel-MLP: A3 -> A4
        k_smlp<<<dim3(576), dim3(512), 0, stream>>>(A3b,
            W0P + (size_t)l*131072, W1P + (size_t)l*262144, WOP + (size_t)l*131072, A4b);
        // S6 H-DFT inv: A4 x THI -> A5
        G(4, A4b, A4b, BIGV, 384, 384, THI, 4096, A5b, 0, nf, nu, 24576, 24576, 512, 384, 0);
        // S7 irdft: A5 x TWI -> YP [pt][128]
        G(5, A5b, A5b, BIGV, 384, 384, TWI, 3072, YP, 0, nf, nu, 23168, 23168, 384, 384, 0);
        // inner skip: CUR = isw*XN + isb + Y
        G(0, XNP, XNP, BIGV, 128, 128, ISWP + (size_t)l*16384, 1024, CURP, 128, isb+l*128, YP, NPAD, NP, 128, 128, 0);
        // norm1
        k_istat<<<dim3(128), blk, 0, stream>>>(CURP, st1);
        k_apply<<<dim3((NP*16+255)/256), blk, 0, stream>>>(CURP, YP, st1, n1w+l*128, n1b+l*128);
        // fc1 + gelu -> BIG [pt][256]
        G(0, YP, YP, BIGV, 128, 128, FC1P + (size_t)l*32768, 2048, BIG, 256, fc1b+l*256, nu, NPAD, NP, 256, 128, 1);
        // fc2 + outer skip(XN) -> CUR
        G(0, BIG, BIG, BIGV, 256, 256, FC2P + (size_t)l*32768, 1024, CURP, 128, fc2b+l*128, XNP, NPAD, NP, 128, 256, 0);
    }
    // decoder conv0 (concat CUR, x) + gelu -> XNP
    G(0, CURP, XT2, 128, 128, 32, DW0P, 1024, XNP, 128, dec_b0, nu, NPAD, NP, 128, 160, 1);
    k_dec1<<<dim3((NP+255)/256), blk, 0, stream>>>(XNP, dec_w1, out);
}

// Round 7
// 1803.651 us; speedup vs baseline: 3.8180x; 1.0411x over previous
//
#include <hip/hip_runtime.h>
#include <math.h>

#define NP 65160        // 181*360
#define NPAD 65280

typedef unsigned short u16;
typedef __attribute__((ext_vector_type(8))) short bf16x8;
typedef __attribute__((ext_vector_type(8))) unsigned short us8;
typedef __attribute__((ext_vector_type(4))) float f32x4;

__device__ __forceinline__ u16 f2bf(float f){
    unsigned u = __builtin_bit_cast(unsigned, f);
    return (u16)((u + 0x7FFFu + ((u>>16)&1u)) >> 16);
}
__device__ __forceinline__ float bf2f(u16 h){
    unsigned u = ((unsigned)h)<<16;
    return __builtin_bit_cast(float, u);
}
__device__ __forceinline__ float gelu_f(float x){
    return 0.5f*x*(1.0f+erff(x*0.70710678118654752f));
}

__global__ void k_zero(u16* __restrict__ p, long n){
    long i = ((long)blockIdx.x*256 + threadIdx.x)*8;
    if(i+8 <= n){ us8 z = {0,0,0,0,0,0,0,0}; *(us8*)(p+i) = z; }
}

// ============ B packs: dst[kg][n][8], k = kg*8+e, zero padded ============
__global__ void k_pack_twf(u16* __restrict__ dst){   // [48][384][8]: k=w, n=2kw+q
    int i = blockIdx.x*256+threadIdx.x; if(i >= 48*384*8) return;
    int e = i&7, n = (i>>3)%384, kg = i/(384*8);
    int k = kg*8+e, kw = n>>1, q = n&1;
    float v = 0.0f;
    if(k < 360 && kw < 181){
        float inv = 1.0f/sqrtf(65160.0f);
        float th = 6.28318530717958647692f*(float)((k*kw)%360)/360.0f;
        v = q ? -sinf(th)*inv : cosf(th)*inv;
    }
    dst[i] = f2bf(v);
}
__global__ void k_pack_thf(u16* __restrict__ dst){   // [64][384][8]: k=2h+q, n=2kh+p
    int i = blockIdx.x*256+threadIdx.x; if(i >= 64*384*8) return;
    int e = i&7, n = (i>>3)%384, kg = i/(384*8);
    int k = kg*8+e;
    float v = 0.0f;
    if(k < 362 && n < 362){
        int h = k>>1, q = k&1, kh = n>>1, p = n&1;
        float th = 6.28318530717958647692f*(float)((h*kh)%181)/181.0f;
        float c = cosf(th), s = sinf(th);
        v = (q==0) ? (p==0? c : -s) : (p==0? s : c);
    }
    dst[i] = f2bf(v);
}
__global__ void k_pack_thi(u16* __restrict__ dst){   // [48][512][8]: k=2kh+p, n=2h+q
    int i = blockIdx.x*256+threadIdx.x; if(i >= 48*512*8) return;
    int e = i&7, n = (i>>3)%512, kg = i/(512*8);
    int k = kg*8+e;
    float v = 0.0f;
    if(k < 362 && n < 362){
        int kh = k>>1, p = k&1, h = n>>1, q = n&1;
        float th = 6.28318530717958647692f*(float)((kh*h)%181)/181.0f;
        float c = cosf(th), s = sinf(th);
        v = (q==0) ? (p==0? c : -s) : (p==0? s : c);
    }
    dst[i] = f2bf(v);
}
__global__ void k_pack_twi(u16* __restrict__ dst){   // [48][384][8]: k=2kw+q, n=w
    int i = blockIdx.x*256+threadIdx.x; if(i >= 48*384*8) return;
    int e = i&7, n = (i>>3)%384, kg = i/(384*8);
    int k = kg*8+e, kw = k>>1, q = k&1;
    float v = 0.0f;
    if(k < 362 && n < 360){
        float inv = 1.0f/sqrtf(65160.0f);
        float eps = (kw==0 || kw==180) ? 1.0f : 2.0f;
        float th = 6.28318530717958647692f*(float)((n*kw)%360)/360.0f;
        v = q ? -eps*sinf(th)*inv : eps*cosf(th)*inv;
    }
    dst[i] = f2bf(v);
}
__global__ void k_pack_cw(const float* __restrict__ src, u16* __restrict__ dst,
                          int CIN, int COUT, int lss, int lsd){
    int z = blockIdx.z;
    int Npad = 2*COUT, KG = (2*CIN)/8;
    int tot = KG*Npad*8;
    int i = blockIdx.x*256+threadIdx.x; if(i >= tot) return;
    int e = i&7, n = (i>>3)%Npad, kg = i/(Npad*8);
    int k = kg*8+e, ci = k>>1, q = k&1, co = n>>1, p = n&1;
    float re = src[(size_t)z*lss + ci*COUT + co];
    float im = src[(size_t)z*lss + CIN*COUT + ci*COUT + co];
    float v = (p==0) ? (q==0? re : -im) : (q==0? im : re);
    dst[(size_t)z*lsd + i] = f2bf(v);
}
__global__ void k_pack_rw(const float* __restrict__ src, u16* __restrict__ dst,
                          int Nn, int Ks, int KG, int lss, int lsd){
    int z = blockIdx.z;
    int tot = KG*Nn*8;
    int i = blockIdx.x*256+threadIdx.x; if(i >= tot) return;
    int e = i&7, n = (i>>3)%Nn, kg = i/(Nn*8);
    int k = kg*8+e;
    float v = (k < Ks) ? src[(size_t)z*lss + n*Ks + k] : 0.0f;
    dst[(size_t)z*lsd + i] = f2bf(v);
}

// ============ pointwise ============
__global__ void k_enc0(const float* __restrict__ x, const float* __restrict__ w,
                       const float* __restrict__ b, u16* __restrict__ out){
    int i = blockIdx.x*256+threadIdx.x;
    if(i >= NP*16) return;
    int p = i>>4, c8 = (i&15)*8;
    float x0 = x[p], x1 = x[NP+p];
    us8 o;
    #pragma unroll
    for(int j=0;j<8;j++){
        int e = c8+j;
        float v = w[e*2]*x0 + w[e*2+1]*x1 + b[e];
        o[j] = f2bf(gelu_f(v));
    }
    *(us8*)(out + (size_t)p*128 + c8) = o;
}
__global__ void k_xt2(const float* __restrict__ x, u16* __restrict__ dst){
    int p = blockIdx.x*256+threadIdx.x; if(p >= NP) return;
    us8 z = {0,0,0,0,0,0,0,0};
    z[0] = f2bf(x[p]); z[1] = f2bf(x[NP+p]);
    *(us8*)(dst + (size_t)p*32) = z;
    us8 z2 = {0,0,0,0,0,0,0,0};
    *(us8*)(dst + (size_t)p*32 + 8)  = z2;
    *(us8*)(dst + (size_t)p*32 + 16) = z2;
    *(us8*)(dst + (size_t)p*32 + 24) = z2;
}
__global__ void k_dec1(const u16* __restrict__ hid, const float* __restrict__ w,
                       float* __restrict__ out){
    int p = blockIdx.x*256+threadIdx.x; if(p >= NP) return;
    float a0=0.0f, a1=0.0f;
    #pragma unroll 4
    for(int k8=0;k8<16;k8++){
        us8 v = *(const us8*)(hid + (size_t)p*128 + k8*8);
        #pragma unroll
        for(int j=0;j<8;j++){
            float f = bf2f(v[j]);
            a0 = fmaf(w[k8*8+j], f, a0);
            a1 = fmaf(w[128+k8*8+j], f, a1);
        }
    }
    out[p] = a0; out[NP+p] = a1;
}

// ============ instance norm ============
__global__ __launch_bounds__(256) void k_istat(const u16* __restrict__ X, float* __restrict__ stat){
    int t = threadIdx.x;
    int c8 = (t&15)*8;
    float s[8], s2[8];
    #pragma unroll
    for(int j=0;j<8;j++){ s[j]=0.0f; s2[j]=0.0f; }
    for(int p = blockIdx.x*16 + (t>>4); p < NP; p += gridDim.x*16){
        us8 v = *(const us8*)(X + (size_t)p*128 + c8);
        #pragma unroll
        for(int j=0;j<8;j++){ float f = bf2f(v[j]); s[j]+=f; s2[j]=fmaf(f,f,s2[j]); }
    }
    __shared__ float L[256][8];
    #pragma unroll
    for(int j=0;j<8;j++) L[t][j]=s[j];
    __syncthreads();
    for(int st=128; st>=16; st>>=1){
        if(t<st){
            #pragma unroll
            for(int j=0;j<8;j++) L[t][j]+=L[t+st][j];
        }
        __syncthreads();
    }
    if(t<16){
        #pragma unroll
        for(int j=0;j<8;j++) atomicAdd(&stat[t*8+j], L[t][j]);
    }
    __syncthreads();
    #pragma unroll
    for(int j=0;j<8;j++) L[t][j]=s2[j];
    __syncthreads();
    for(int st=128; st>=16; st>>=1){
        if(t<st){
            #pragma unroll
            for(int j=0;j<8;j++) L[t][j]+=L[t+st][j];
        }
        __syncthreads();
    }
    if(t<16){
        #pragma unroll
        for(int j=0;j<8;j++) atomicAdd(&stat[128+t*8+j], L[t][j]);
    }
}
__global__ __launch_bounds__(256) void k_apply_t(
    const u16* __restrict__ X, u16* __restrict__ outp, u16* __restrict__ outc,
    const float* __restrict__ stat, const float* __restrict__ gw, const float* __restrict__ gb)
{
    __shared__ u16 T[128][72];
    __shared__ float SA_[128], SB_[128];
    int t = threadIdx.x;
    if(t < 128){
        float mu = stat[t]*(1.0f/(float)NP);
        float var = stat[128+t]*(1.0f/(float)NP) - mu*mu;
        var = fmaxf(var, 0.0f);
        float rstd = 1.0f/sqrtf(var + 1e-6f);
        float a = rstd*gw[t];
        SA_[t] = a; SB_[t] = gb[t] - mu*a;
    }
    __syncthreads();
    int p0 = blockIdx.x*64;
    int pl = t>>2, cc = (t&3)*32;
    int p = p0 + pl;
    if(p < NP){
        #pragma unroll
        for(int jj=0;jj<4;jj++){
            us8 v = *(const us8*)(X + (size_t)p*128 + cc + jj*8);
            us8 o;
            #pragma unroll
            for(int j=0;j<8;j++){
                int c = cc + jj*8 + j;
                o[j] = f2bf(fmaf(bf2f(v[j]), SA_[c], SB_[c]));
            }
            *(us8*)(outp + (size_t)p*128 + cc + jj*8) = o;
            #pragma unroll
            for(int j=0;j<8;j++) T[cc+jj*8+j][pl] = o[j];
        }
    }
    __syncthreads();
    int c = t>>1, half = t&1;
    int pbase = p0 + half*32;
    #pragma unroll
    for(int jj=0;jj<4;jj++){
        int pp = pbase + jj*8;
        if(pp + 8 <= NP){
            int hh = pp/360, ww = pp - hh*360;
            *(us8*)(outc + ((size_t)c*256 + hh)*384 + ww) = *(const us8*)(&T[c][half*32 + jj*8]);
        }
    }
}
__global__ __launch_bounds__(256) void k_apply(
    const u16* __restrict__ X, u16* __restrict__ outp,
    const float* __restrict__ stat, const float* __restrict__ gw, const float* __restrict__ gb)
{
    __shared__ float SA_[128], SB_[128];
    int t = threadIdx.x;
    if(t < 128){
        float mu = stat[t]*(1.0f/(float)NP);
        float var = stat[128+t]*(1.0f/(float)NP) - mu*mu;
        var = fmaxf(var, 0.0f);
        float rstd = 1.0f/sqrtf(var + 1e-6f);
        float a = rstd*gw[t];
        SA_[t] = a; SB_[t] = gb[t] - mu*a;
    }
    __syncthreads();
    int i = blockIdx.x*256 + t;
    if(i >= NP*16) return;
    int p = i>>4, c8 = (i&15)*8;
    us8 v = *(const us8*)(X + (size_t)p*128 + c8);
    us8 o;
    #pragma unroll
    for(int j=0;j<8;j++) o[j] = f2bf(fmaf(bf2f(v[j]), SA_[c8+j], SB_[c8+j]));
    *(us8*)(outp + (size_t)p*128 + c8) = o;
}
__global__ __launch_bounds__(256) void k_post(const float* __restrict__ src, u16* __restrict__ dst){
    __shared__ u16 T[128][72];
    int t = threadIdx.x;
    int p0 = blockIdx.x*64;
    int c = t>>1, half = t&1;
    int pbase = p0 + half*32;
    #pragma unroll
    for(int jj=0;jj<4;jj++){
        int pp = pbase + jj*8;
        us8 v = {0,0,0,0,0,0,0,0};
        if(pp + 8 <= NP){
            #pragma unroll
            for(int j=0;j<8;j++) v[j] = f2bf(src[(size_t)c*NP + pp + j]);
        }
        *(us8*)(&T[c][half*32 + jj*8]) = v;
    }
    __syncthreads();
    int pl = t>>2, cc = (t&3)*32;
    int p = p0 + pl;
    if(p < NP){
        #pragma unroll
        for(int jj=0;jj<4;jj++){
            us8 o;
            #pragma unroll
            for(int j=0;j<8;j++) o[j] = T[cc+jj*8+j][pl];
            *(us8*)(dst + (size_t)p*128 + cc + jj*8) = o;
        }
    }
}

// ============ fused spectral channel-MLP (S3+S4+S5), 16 waves ============
// per block: 64 spectral points (m = kw*192+kh); H1/H2 in LDS (520-stride:
// 65 16B-units/row, 65%8==1 -> A-reads conflict-free).
__global__ __launch_bounds__(1024) void k_smlp(
    const u16* __restrict__ A3, const u16* __restrict__ W0,
    const u16* __restrict__ W1, const u16* __restrict__ WO,
    u16* __restrict__ A4)
{
    __shared__ u16 Hs0[64][520];
    __shared__ u16 Hs1[64][520];
    int tid = threadIdx.x;
    int l = tid & 63, wv = tid >> 6;     // 16 waves
    int wm = wv >> 2, wn = wv & 3;       // 4 x 4
    int lm = l & 15, kg = l >> 4;
    int m0 = blockIdx.x * 64;

    // ---- stage 1: Hs0[64][512] = A3 x W0 (K=256), CReLU even col ----
    f32x4 acc[8];
    #pragma unroll
    for(int j=0;j<8;j++) acc[j] = (f32x4){0.f,0.f,0.f,0.f};
    {
        const u16* ap = A3 + (size_t)(m0 + wm*16 + lm)*256 + kg*8;
        #pragma unroll
        for(int k0=0;k0<256;k0+=32){
            bf16x8 af = *(const bf16x8*)(ap + k0);
            const u16* Bb = W0 + (size_t)((k0>>3)+kg)*4096 + (wn*128+lm)*8;
            #pragma unroll
            for(int j2=0;j2<8;j2++){
                bf16x8 bf = *(const bf16x8*)(Bb + j2*128);
                acc[j2] = __builtin_amdgcn_mfma_f32_16x16x32_bf16(af, bf, acc[j2], 0,0,0);
            }
        }
    }
    #pragma unroll
    for(int j2=0;j2<8;j2++)
        #pragma unroll
        for(int r=0;r<4;r++){
            int row = wm*16 + kg*4 + r;
            int col = wn*128 + j2*16 + lm;
            float v = acc[j2][r];
            if(!(col&1)) v = fmaxf(v, 0.0f);
            Hs0[row][col] = f2bf(v);
        }
    __syncthreads();
    // ---- stage 2: Hs1 = Hs0 x W1 (K=512), CReLU even col ----
    #pragma unroll
    for(int j=0;j<8;j++) acc[j] = (f32x4){0.f,0.f,0.f,0.f};
    for(int k0=0;k0<512;k0+=32){
        bf16x8 af = *(const bf16x8*)(&Hs0[wm*16 + lm][k0 + kg*8]);
        const u16* Bb = W1 + (size_t)((k0>>3)+kg)*4096 + (wn*128+lm)*8;
        #pragma unroll
        for(int j2=0;j2<8;j2++){
            bf16x8 bf = *(const bf16x8*)(Bb + j2*128);
            acc[j2] = __builtin_amdgcn_mfma_f32_16x16x32_bf16(af, bf, acc[j2], 0,0,0);
        }
    }
    #pragma unroll
    for(int j2=0;j2<8;j2++)
        #pragma unroll
        for(int r=0;r<4;r++){
            int row = wm*16 + kg*4 + r;
            int col = wn*128 + j2*16 + lm;
            float v = acc[j2][r];
            if(!(col&1)) v = fmaxf(v, 0.0f);
            Hs1[row][col] = f2bf(v);
        }
    __syncthreads();
    // ---- stage 3: O[64][256] = Hs1 x WO (K=512) ----
    f32x4 acc3[4];
    #pragma unroll
    for(int j=0;j<4;j++) acc3[j] = (f32x4){0.f,0.f,0.f,0.f};
    for(int k0=0;k0<512;k0+=32){
        bf16x8 af = *(const bf16x8*)(&Hs1[wm*16 + lm][k0 + kg*8]);
        const u16* Bb = WO + (size_t)((k0>>3)+kg)*2048 + (wn*64+lm)*8;
        #pragma unroll
        for(int j2=0;j2<4;j2++){
            bf16x8 bf = *(const bf16x8*)(Bb + j2*128);
            acc3[j2] = __builtin_amdgcn_mfma_f32_16x16x32_bf16(af, bf, acc3[j2], 0,0,0);
        }
    }
    __syncthreads();
    #pragma unroll
    for(int j2=0;j2<4;j2++)
        #pragma unroll
        for(int r=0;r<4;r++)
            Hs0[wm*16 + kg*4 + r][wn*64 + j2*16 + lm] = f2bf(acc3[j2][r]);
    __syncthreads();
    // ---- coalesced store: A4[(c*192+kw)*384 + 2kh+p] ----
    if(tid < 512){
        int kw = m0 / 192;
        int kh0 = m0 - kw*192;
        int c = tid >> 2, q = tid & 3;
        long base = ((long)(c*192 + kw))*384 + 2*(kh0 + q*16);
        #pragma unroll
        for(int jj=0;jj<4;jj++){
            us8 v;
            #pragma unroll
            for(int i=0;i<4;i++){
                v[2*i]   = Hs0[q*16 + jj*4 + i][2*c];
                v[2*i+1] = Hs0[q*16 + jj*4 + i][2*c+1];
            }
            *(us8*)(A4 + base + jj*8) = v;
        }
    }
}

// ============ fused spatial MLP: fc1+gelu+fc2+outer-skip ============
// per block: 64 points; H[64][256] in LDS (264-stride: 33 units, 33%8==1).
__global__ __launch_bounds__(512) void k_pmlp(
    const u16* __restrict__ A, const u16* __restrict__ FC1, const u16* __restrict__ FC2,
    const float* __restrict__ b1, const float* __restrict__ b2,
    const u16* __restrict__ addb, u16* __restrict__ OUT)
{
    __shared__ u16 Hs[64][264];
    int tid = threadIdx.x;
    int l = tid & 63, wv = tid >> 6;     // 8 waves
    int wm = wv >> 1, wn = wv & 1;
    int lm = l & 15, kg = l >> 4;
    int m0 = blockIdx.x * 64;

    // stage 1: Hs[64][256] = A[64][128] x FC1 + b1, gelu
    f32x4 acc[8];
    #pragma unroll
    for(int j=0;j<8;j++) acc[j] = (f32x4){0.f,0.f,0.f,0.f};
    {
        const u16* ap = A + (size_t)(m0 + wm*16 + lm)*128 + kg*8;
        #pragma unroll
        for(int k0=0;k0<128;k0+=32){
            bf16x8 af = *(const bf16x8*)(ap + k0);
            const u16* Bb = FC1 + (size_t)((k0>>3)+kg)*2048 + (wn*128+lm)*8;
            #pragma unroll
            for(int j2=0;j2<8;j2++){
                bf16x8 bf = *(const bf16x8*)(Bb + j2*128);
                acc[j2] = __builtin_amdgcn_mfma_f32_16x16x32_bf16(af, bf, acc[j2], 0,0,0);
            }
        }
    }
    #pragma unroll
    for(int j2=0;j2<8;j2++)
        #pragma unroll
        for(int r=0;r<4;r++){
            int row = wm*16 + kg*4 + r;
            int col = wn*128 + j2*16 + lm;
            Hs[row][col] = f2bf(gelu_f(acc[j2][r] + b1[col]));
        }
    __syncthreads();
    // stage 2: OUT[64][128] = Hs x FC2 (K=256) + b2 + addb
    f32x4 acc2[4];
    #pragma unroll
    for(int j=0;j<4;j++) acc2[j] = (f32x4){0.f,0.f,0.f,0.f};
    for(int k0=0;k0<256;k0+=32){
        bf16x8 af = *(const bf16x8*)(&Hs[wm*16 + lm][k0 + kg*8]);
        const u16* Bb = FC2 + (size_t)((k0>>3)+kg)*1024 + (wn*64+lm)*8;
        #pragma unroll
        for(int j2=0;j2<4;j2++){
            bf16x8 bf = *(const bf16x8*)(Bb + j2*128);
            acc2[j2] = __builtin_amdgcn_mfma_f32_16x16x32_bf16(af, bf, acc2[j2], 0,0,0);
        }
    }
    #pragma unroll
    for(int j2=0;j2<4;j2++)
        #pragma unroll
        for(int r=0;r<4;r++){
            int row = wm*16 + kg*4 + r;
            long p = m0 + row;
            if(p < NP){
                int n = wn*64 + j2*16 + lm;
                float v = acc2[j2][r] + b2[n] + bf2f(addb[p*128 + n]);
                OUT[p*128 + n] = f2bf(v);
            }
        }
}

// ============ MFMA GEMM, templated on store mode ============
// TMODE 0: C[m*cstr + n] (bias/gelu/relu-even/addb), NO LDS
// TMODE 1: m=c*256+h,  n=2kw+q -> C[(kw*128+c)*512 + 2h+q]
// TMODE 2: m=kw*128+c, n=2kh+p -> C[(kw*192+kh)*256 + 2c+p]
// TMODE 4: m=c*192+kw, n=2h+q  -> C[(h*128+c)*384 + 2kw+q]
// TMODE 5: m=h*128+c,  n=w     -> C[(h*360+w)*128 + c], w<360
template<int TMODE>
__global__ __launch_bounds__(256) void k_gemm(
    const u16* __restrict__ A1, const u16* __restrict__ A2, int aksplit, int astr, int a2str,
    const u16* __restrict__ B, int bkstr,
    u16* __restrict__ C, int cstr,
    const float* __restrict__ bias, const u16* __restrict__ addb,
    int Mvalid, int N, int Kpad, int flags)
{
    int tid = threadIdx.x;
    int l = tid & 63, wv = tid >> 6;
    int wm = wv >> 1, wn = wv & 1;
    int lm = l & 15, kgl = l >> 4;
    int m0 = blockIdx.y*128 + wm*64;
    int n0 = blockIdx.x*128 + wn*64;

    int ab1[4], ab2[4];
    #pragma unroll
    for(int i2=0;i2<4;i2++){
        int mi = m0 + i2*16 + lm;
        ab1[i2] = mi*astr;
        ab2[i2] = mi*a2str;
    }
    int bn[4];
    #pragma unroll
    for(int j2=0;j2<4;j2++) bn[j2] = (n0 + j2*16 + lm)*8;

    f32x4 acc[4][4];
    #pragma unroll
    for(int i2=0;i2<4;i2++)
        #pragma unroll
        for(int j2=0;j2<4;j2++)
            acc[i2][j2] = (f32x4){0.0f,0.0f,0.0f,0.0f};

    for(int k0=0; k0<Kpad; k0+=32){
        int kk = k0 + kgl*8;
        bool s1v = kk < aksplit;
        const u16* Ab = s1v ? A1 : A2;
        int kof = s1v ? kk : kk - aksplit;
        bf16x8 af[4];
        #pragma unroll
        for(int i2=0;i2<4;i2++)
            af[i2] = *(const bf16x8*)(Ab + (s1v ? ab1[i2] : ab2[i2]) + kof);
        const u16* Bb = B + (size_t)((k0>>3) + kgl)*bkstr;
        bf16x8 bf[4];
        #pragma unroll
        for(int j2=0;j2<4;j2++)
            bf[j2] = *(const bf16x8*)(Bb + bn[j2]);
        #pragma unroll
        for(int i2=0;i2<4;i2++)
            #pragma unroll
            for(int j2=0;j2<4;j2++)
                acc[i2][j2] = __builtin_amdgcn_mfma_f32_16x16x32_bf16(af[i2], bf[j2], acc[i2][j2], 0,0,0);
    }

    if constexpr (TMODE == 0){
        #pragma unroll
        for(int i2=0;i2<4;i2++){
            #pragma unroll
            for(int r=0;r<4;r++){
                int m = m0 + i2*16 + kgl*4 + r;
                if(m >= Mvalid) continue;
                long mb = (long)m*cstr;
                #pragma unroll
                for(int j2=0;j2<4;j2++){
                    int n = n0 + j2*16 + lm;
                    if(n >= N) continue;
                    float v = acc[i2][j2][r];
                    if(bias) v += bias[n];
                    if(flags & 1) v = gelu_f(v);
                    if((flags & 2) && !(n & 1)) v = fmaxf(v, 0.0f);
                    long ca = mb + n;
                    if(addb) v += bf2f(addb[ca]);
                    C[ca] = f2bf(v);
                }
            }
        }
    } else {
        __shared__ u16 Tt[128][132];
        #pragma unroll
        for(int i2=0;i2<4;i2++)
            #pragma unroll
            for(int j2=0;j2<4;j2++)
                #pragma unroll
                for(int r=0;r<4;r++)
                    Tt[wm*64+i2*16+kgl*4+r][wn*64+j2*16+lm] = f2bf(acc[i2][j2][r]);
        __syncthreads();
        int m0b = blockIdx.y*128, n0b = blockIdx.x*128;
        if constexpr (TMODE <= 4){
            #pragma unroll
            for(int it=0; it<8; it++){
                int g = tid + it*256;
                int gn = g & 63, gm = g >> 6;
                int ml = gm*4, nl = gn*2;
                int mg = m0b + ml, ng = n0b + nl;
                long base;
                if constexpr (TMODE == 1){
                    int c = mg>>8, h = mg&255, kw = ng>>1;
                    base = ((long)(kw*128 + c))*512 + 2*h;
                } else if constexpr (TMODE == 2){
                    int kw = mg>>7, c = mg&127, kh = ng>>1;
                    base = ((long)(kw*192 + kh))*256 + 2*c;
                } else {
                    int c = (int)(((unsigned)mg*43691u)>>23);
                    int kw = mg - c*192;
                    int h = ng>>1;
                    base = ((long)(h*128 + c))*384 + 2*kw;
                }
                us8 v;
                #pragma unroll
                for(int i=0;i<4;i++){
                    v[2*i]   = Tt[ml+i][nl];
                    v[2*i+1] = Tt[ml+i][nl+1];
                }
                *(us8*)(C + base) = v;
            }
        } else {
            #pragma unroll
            for(int it=0; it<8; it++){
                int g = tid + it*256;
                int nl = g & 127, gm = g >> 7;
                int ml = gm*8;
                int mg = m0b + ml, ng = n0b + nl;
                if(ng < 360){
                    int h = mg >> 7;
                    long base = ((long)(h*360 + ng))*128 + (mg & 127);
                    us8 v;
                    #pragma unroll
                    for(int j=0;j<8;j++) v[j] = Tt[ml+j][nl];
                    *(us8*)(C + base) = v;
                }
            }
        }
    }
}

// ============ launch ============
extern "C" void kernel_launch(void* const* d_in, const int* in_sizes, int n_in,
                              void* d_out, int out_size, void* d_ws, size_t ws_size,
                              hipStream_t stream) {
    const float* x       = (const float*)d_in[0];
    const float* enc_w0  = (const float*)d_in[1];
    const float* enc_b0  = (const float*)d_in[2];
    const float* enc_w1  = (const float*)d_in[3];
    const float* pos     = (const float*)d_in[4];
    const float* n0w     = (const float*)d_in[5];
    const float* n0b     = (const float*)d_in[6];
    const float* w0      = (const float*)d_in[7];
    const float* w1      = (const float*)d_in[8];
    const float* wout    = (const float*)d_in[9];
    const float* isw     = (const float*)d_in[10];
    const float* isb     = (const float*)d_in[11];
    const float* n1w     = (const float*)d_in[12];
    const float* n1b     = (const float*)d_in[13];
    const float* fc1w    = (const float*)d_in[14];
    const float* fc1b    = (const float*)d_in[15];
    const float* fc2w    = (const float*)d_in[16];
    const float* fc2b    = (const float*)d_in[17];
    const float* dec_w0  = (const float*)d_in[18];
    const float* dec_b0  = (const float*)d_in[19];
    const float* dec_w1  = (const float*)d_in[20];
    float* out = (float*)d_out;

    u16* ws = (u16*)d_ws;
    size_t off = 0;
    auto al = [&](size_t n){ u16* p = ws + off; off += (n + 63) & ~(size_t)63; return p; };
    u16* TWF  = al(147456);
    u16* THF  = al(196608);
    u16* THI  = al(196608);
    u16* TWI  = al(147456);
    u16* W0P  = al(524288);
    u16* W1P  = al(1048576);
    u16* WOP  = al(524288);
    u16* ISWP = al(65536);
    u16* FC1P = al(131072);
    u16* FC2P = al(131072);
    u16* EW1P = al(16384);
    u16* DW0P = al(20480);
    u16* POSP = al((size_t)NPAD*128);
    u16* XT2  = al((size_t)NPAD*32);
    u16* CURP = al((size_t)NPAD*128);
    u16* XNP  = al((size_t)NPAD*128);
    u16* YP   = al((size_t)NPAD*128);
    u16* XNC  = al((size_t)32768*384);   // [c*256+h][384]
    u16* A2b  = al((size_t)24576*512);   // [kw*128+c][2h+q]  (also A5: [h*128+c][2kw+q])
    u16* A3b  = al((size_t)36864*256);   // [kw*192+kh][2c+p]
    u16* A4b  = al((size_t)24576*384);   // [c*192+kw][2kh+p]
    u16* BIG  = al((size_t)NPAD*128);    // ENC [pt][128]
    u16* IST  = al(4096);
    float* ISTAT = (float*)IST;
    u16* A5b = A2b;
    u16* ENC = BIG;

    dim3 blk(256);
    k_zero<<<dim3(6144), blk, 0, stream>>>(XNC, (long)32768*384);
    k_zero<<<dim3(2),    blk, 0, stream>>>(IST, 4096);

    // packs
    k_pack_twf<<<dim3((147456+255)/256), blk, 0, stream>>>(TWF);
    k_pack_thf<<<dim3((196608+255)/256), blk, 0, stream>>>(THF);
    k_pack_thi<<<dim3((196608+255)/256), blk, 0, stream>>>(THI);
    k_pack_twi<<<dim3((147456+255)/256), blk, 0, stream>>>(TWI);
    k_pack_cw<<<dim3((131072+255)/256,1,4), blk, 0, stream>>>(w0,   W0P, 128, 256, 2*128*256, 131072);
    k_pack_cw<<<dim3((262144+255)/256,1,4), blk, 0, stream>>>(w1,   W1P, 256, 256, 2*256*256, 262144);
    k_pack_cw<<<dim3((131072+255)/256,1,4), blk, 0, stream>>>(wout, WOP, 256, 128, 2*256*128, 131072);
    k_pack_rw<<<dim3((16384+255)/256,1,4),  blk, 0, stream>>>(isw,  ISWP, 128, 128, 16, 128*128, 16384);
    k_pack_rw<<<dim3((32768+255)/256,1,4),  blk, 0, stream>>>(fc1w, FC1P, 256, 128, 16, 256*128, 32768);
    k_pack_rw<<<dim3((32768+255)/256,1,4),  blk, 0, stream>>>(fc2w, FC2P, 128, 256, 32, 128*256, 32768);
    k_pack_rw<<<dim3((16384+255)/256,1,1),  blk, 0, stream>>>(enc_w1, EW1P, 128, 128, 16, 0, 0);
    k_pack_rw<<<dim3((20480+255)/256,1,1),  blk, 0, stream>>>(dec_w0, DW0P, 128, 130, 20, 0, 0);
    k_post<<<dim3(1019), blk, 0, stream>>>(pos, POSP);
    k_xt2 <<<dim3((NP+255)/256), blk, 0, stream>>>(x, XT2);

    const u16* nu = nullptr;
    const float* nf = nullptr;
    const int BIGV = 1<<28;
    auto G = [&](int tmode, const u16* A1v, const u16* A2v, int aksplit, int astr, int a2str,
                 const u16* Bv, int bkstr, u16* Cv, int cstr,
                 const float* bias, const u16* addb,
                 int Mgrid, int Mvalid, int N, int Kpad, int flags){
        dim3 g((N+127)/128, (Mgrid+127)/128, 1);
        switch(tmode){
        case 0: k_gemm<0><<<g, blk, 0, stream>>>(A1v,A2v,aksplit,astr,a2str,Bv,bkstr,Cv,cstr,bias,addb,Mvalid,N,Kpad,flags); break;
        case 1: k_gemm<1><<<g, blk, 0, stream>>>(A1v,A2v,aksplit,astr,a2str,Bv,bkstr,Cv,cstr,bias,addb,Mvalid,N,Kpad,flags); break;
        case 2: k_gemm<2><<<g, blk, 0, stream>>>(A1v,A2v,aksplit,astr,a2str,Bv,bkstr,Cv,cstr,bias,addb,Mvalid,N,Kpad,flags); break;
        case 4: k_gemm<4><<<g, blk, 0, stream>>>(A1v,A2v,aksplit,astr,a2str,Bv,bkstr,Cv,cstr,bias,addb,Mvalid,N,Kpad,flags); break;
        case 5: k_gemm<5><<<g, blk, 0, stream>>>(A1v,A2v,aksplit,astr,a2str,Bv,bkstr,Cv,cstr,bias,addb,Mvalid,N,Kpad,flags); break;
        }
    };

    // encoder
    k_enc0<<<dim3((NP*16+255)/256), blk, 0, stream>>>(x, enc_w0, enc_b0, ENC);
    G(0, ENC, ENC, BIGV, 128, 128, EW1P, 1024, CURP, 128, nf, POSP, NPAD, NP, 128, 128, 0);

    for(int l=0; l<4; l++){
        float* st0 = ISTAT + (2*l)*256;
        float* st1 = ISTAT + (2*l+1)*256;
        k_istat<<<dim3(128), blk, 0, stream>>>(CURP, st0);
        k_apply_t<<<dim3(1019), blk, 0, stream>>>(CURP, XNP, XNC, st0, n0w+l*128, n0b+l*128);
        // S1 rdft: XNC x TWF -> A2
        G(1, XNC, XNC, BIGV, 384, 384, TWF, 3072, A2b, 0, nf, nu, 32768, 32768, 384, 384, 0);
        // S2 H-DFT fwd: A2 x THF -> A3
        G(2, A2b, A2b, BIGV, 512, 512, THF, 3072, A3b, 0, nf, nu, 24576, 24576, 384, 512, 0);
        // fused spectral channel-MLP: A3 -> A4
        k_smlp<<<dim3(576), dim3(1024), 0, stream>>>(A3b,
            W0P + (size_t)l*131072, W1P + (size_t)l*262144, WOP + (size_t)l*131072, A4b);
        // S6 H-DFT inv: A4 x THI -> A5
        G(4, A4b, A4b, BIGV, 384, 384, THI, 4096, A5b, 0, nf, nu, 24576, 24576, 512, 384, 0);
        // S7 irdft: A5 x TWI -> YP [pt][128]
        G(5, A5b, A5b, BIGV, 384, 384, TWI, 3072, YP, 0, nf, nu, 23168, 23168, 384, 384, 0);
        // inner skip: CUR = isw*XN + isb + Y
        G(0, XNP, XNP, BIGV, 128, 128, ISWP + (size_t)l*16384, 1024, CURP, 128, isb+l*128, YP, NPAD, NP, 128, 128, 0);
        // norm1
        k_istat<<<dim3(128), blk, 0, stream>>>(CURP, st1);
        k_apply<<<dim3((NP*16+255)/256), blk, 0, stream>>>(CURP, YP, st1, n1w+l*128, n1b+l*128);
        // fused spatial MLP: fc1+gelu+fc2+outer-skip(XNP) -> CURP
        k_pmlp<<<dim3(1019), dim3(512), 0, stream>>>(YP,
            FC1P + (size_t)l*32768, FC2P + (size_t)l*32768,
            fc1b + l*256, fc2b + l*128, XNP, CURP);
    }
    // decoder conv0 (concat CUR, x) + gelu -> XNP
    G(0, CURP, XT2, 128, 128, 32, DW0P, 1024, XNP, 128, dec_b0, nu, NPAD, NP, 128, 160, 1);
    k_dec1<<<dim3((NP+255)/256), blk, 0, stream>>>(XNP, dec_w1, out);
}